// Round 18
// baseline (517.087 us; speedup 1.0000x reference)
//
#include <hip/hip_runtime.h>
#include <hip/hip_bf16.h>

#define CC 64
#define WPAD 74

typedef __attribute__((ext_vector_type(8))) short s16x8;
typedef __attribute__((ext_vector_type(4))) float f32x4;

__device__ __forceinline__ unsigned short f2b(float f) {   // f32 -> bf16 via HW cvt (RNE)
    __bf16 h = (__bf16)f;
    return __builtin_bit_cast(unsigned short, h);
}
__device__ __forceinline__ float b2f(unsigned short b) {   // bf16 bits -> f32
    return __uint_as_float((unsigned)b << 16);
}
__device__ __forceinline__ unsigned fmono(float f) {       // order-preserving f32->u32
    unsigned u = __float_as_uint(f);
    return u ^ ((unsigned)((int)u >> 31) | 0x80000000u);
}

// ---- node kernel (MFMA) + fused dst-histogram --------------------------------------------
__global__ __launch_bounds__(256, 2) void node_mfma_kernel(
    const float* __restrict__ x,
    const float* __restrict__ W_in, const float* __restrict__ b_in,
    const float* __restrict__ W_src, const float* __restrict__ W_dst,
    const float* __restrict__ W_lin, const float* __restrict__ aW1,
    unsigned short* __restrict__ ASb, unsigned short* __restrict__ ADb,
    unsigned short* __restrict__ xvb,
    const int* __restrict__ ei, unsigned* __restrict__ cnt, int N, int E)
{
    const int tid = threadIdx.x;
    const int lane = tid & 63;
    const int wid  = tid >> 6;
    const int lm = lane & 15;
    const int lg = lane >> 4;

    __shared__ __align__(16) unsigned short swt[5][64 * WPAD];
    __shared__ __align__(16) unsigned short tb[4][16 * WPAD];

    {
        const float* Wr[4] = {W_in, W_src, W_dst, W_lin};
        #pragma unroll
        for (int w = 0; w < 4; ++w)
            for (int idx = tid; idx < 4096; idx += 256) {
                int o = idx >> 6, k = idx & 63;
                swt[w][o*WPAD + k] = f2b(Wr[w][(size_t)o*64 + k]);
            }
        for (int idx = tid; idx < 4096; idx += 256) {
            int k = idx >> 6, o = idx & 63;
            swt[4][o*WPAD + k] = f2b(aW1[idx]);     // aW1[k][o]
        }
    }
    __syncthreads();

    const int wbase = blockIdx.x * 64 + wid * 16;
    unsigned short* tbw = tb[wid];

    if (wbase < N) {
        float bin[4];
        #pragma unroll
        for (int tt = 0; tt < 4; ++tt) bin[tt] = b_in[lm + 16*tt];

        const int xrow = min(wbase + lm, N-1);
        const float* xp = &x[(size_t)xrow*CC];
        float4 a0 = *(const float4*)&xp[lg*8];
        float4 a1 = *(const float4*)&xp[lg*8 + 4];
        float4 a2 = *(const float4*)&xp[32 + lg*8];
        float4 a3 = *(const float4*)&xp[32 + lg*8 + 4];
        s16x8 Xlo, Xhi;
        Xlo[0]=(short)f2b(a0.x); Xlo[1]=(short)f2b(a0.y); Xlo[2]=(short)f2b(a0.z); Xlo[3]=(short)f2b(a0.w);
        Xlo[4]=(short)f2b(a1.x); Xlo[5]=(short)f2b(a1.y); Xlo[6]=(short)f2b(a1.z); Xlo[7]=(short)f2b(a1.w);
        Xhi[0]=(short)f2b(a2.x); Xhi[1]=(short)f2b(a2.y); Xhi[2]=(short)f2b(a2.z); Xhi[3]=(short)f2b(a2.w);
        Xhi[4]=(short)f2b(a3.x); Xhi[5]=(short)f2b(a3.y); Xhi[6]=(short)f2b(a3.z); Xhi[7]=(short)f2b(a3.w);

        auto mm = [&](s16x8 alo, s16x8 ahi, int w, f32x4* zz) {
            #pragma unroll
            for (int tt = 0; tt < 4; ++tt) {
                s16x8 b0 = *(const s16x8*)&swt[w][(lm + 16*tt)*WPAD + lg*8];
                s16x8 b1 = *(const s16x8*)&swt[w][(lm + 16*tt)*WPAD + 32 + lg*8];
                f32x4 z = {0.f, 0.f, 0.f, 0.f};
                z = __builtin_amdgcn_mfma_f32_16x16x32_bf16(alo, b0, z, 0, 0, 0);
                zz[tt] = __builtin_amdgcn_mfma_f32_16x16x32_bf16(ahi, b1, z, 0, 0, 0);
            }
        };
        auto transpose = [&](const f32x4* zz, s16x8& olo, s16x8& ohi) {
            #pragma unroll
            for (int tt = 0; tt < 4; ++tt)
                #pragma unroll
                for (int r = 0; r < 4; ++r)
                    tbw[(lg*4+r)*WPAD + lm + 16*tt] = f2b(zz[tt][r]);
            __builtin_amdgcn_wave_barrier();
            olo = *(const s16x8*)&tbw[lm*WPAD + lg*8];
            ohi = *(const s16x8*)&tbw[lm*WPAD + 32 + lg*8];
            __builtin_amdgcn_wave_barrier();
        };
        auto store_perm = [&](const f32x4* zz, unsigned short* out) {
            #pragma unroll
            for (int r = 0; r < 4; ++r) {
                int n = wbase + lg*4 + r;
                if (n < N) {
                    ushort4 v = make_ushort4(f2b(zz[0][r]), f2b(zz[1][r]),
                                             f2b(zz[2][r]), f2b(zz[3][r]));
                    *(ushort4*)&out[(size_t)n*CC + lm*4] = v;
                }
            }
        };

        f32x4 zh[4], zt[4], zo[4];
        mm(Xlo, Xhi, 0, zh);
        #pragma unroll
        for (int tt = 0; tt < 4; ++tt)
            #pragma unroll
            for (int r = 0; r < 4; ++r)
                zh[tt][r] = fmaxf(zh[tt][r] + bin[tt], 0.f);
        s16x8 Hlo, Hhi;
        transpose(zh, Hlo, Hhi);

        mm(Hlo, Hhi, 1, zt);
        { s16x8 Tlo, Thi; transpose(zt, Tlo, Thi); mm(Tlo, Thi, 4, zo); }
        store_perm(zo, ASb);

        mm(Hlo, Hhi, 2, zt);
        { s16x8 Tlo, Thi; transpose(zt, Tlo, Thi); mm(Tlo, Thi, 4, zo); }
        store_perm(zo, ADb);

        mm(Hlo, Hhi, 3, zo);
        store_perm(zo, xvb);
    }

    const int total = E + N;
    for (int e = blockIdx.x*256 + tid; e < total; e += gridDim.x*256) {
        int d = (e < E) ? min(max(ei[(size_t)E + e], 0), N-1) : (e - E);
        atomicAdd(&cnt[d], 1u);
    }
}

// ---- exclusive scan (3 kernels) + scatter ------------------------------------------------
#define SCAN_T 256
__global__ __launch_bounds__(SCAN_T) void scan1_kernel(
    const unsigned* __restrict__ cnt, unsigned* __restrict__ chunk_off,
    unsigned* __restrict__ partials, int n)
{
    __shared__ unsigned sh[SCAN_T];
    const int t = threadIdx.x, b0 = blockIdx.x * (SCAN_T*4);
    unsigned v[4], s = 0;
    #pragma unroll
    for (int i = 0; i < 4; ++i) {
        int idx = b0 + t*4 + i;
        v[i] = (idx < n) ? cnt[idx] : 0u;
        s += v[i];
    }
    sh[t] = s; __syncthreads();
    for (int d = 1; d < SCAN_T; d <<= 1) {
        unsigned xv = (t >= d) ? sh[t-d] : 0u;
        __syncthreads();
        sh[t] += xv;
        __syncthreads();
    }
    unsigned run = (t > 0) ? sh[t-1] : 0u;
    #pragma unroll
    for (int i = 0; i < 4; ++i) {
        int idx = b0 + t*4 + i;
        if (idx < n) chunk_off[idx] = run;
        run += v[i];
    }
    if (t == SCAN_T-1) partials[blockIdx.x] = sh[SCAN_T-1];
}

__global__ __launch_bounds__(1024) void scan2_kernel(unsigned* __restrict__ partials, int nb)
{
    __shared__ unsigned sh[1024];
    const int t = threadIdx.x;
    sh[t] = (t < nb) ? partials[t] : 0u; __syncthreads();
    for (int d = 1; d < 1024; d <<= 1) {
        unsigned xv = (t >= d) ? sh[t-d] : 0u;
        __syncthreads();
        sh[t] += xv;
        __syncthreads();
    }
    if (t < nb) partials[t] = (t > 0) ? sh[t-1] : 0u;
}

__global__ __launch_bounds__(256) void scan3_kernel(
    const unsigned* __restrict__ chunk_off, const unsigned* __restrict__ partials,
    unsigned* __restrict__ cursor, int n)
{
    int i = blockIdx.x*256 + threadIdx.x;
    if (i < n) cursor[i] = chunk_off[i] + partials[i >> 10];
}

__global__ __launch_bounds__(256) void scatter_kernel(
    const int* __restrict__ ei, unsigned* __restrict__ cursor,
    int2* __restrict__ rec, int N, int E)
{
    const int total = E + N;
    for (int e = blockIdx.x*256 + threadIdx.x; e < total; e += gridDim.x*256) {
        int s, d;
        if (e < E) {
            s = min(max(ei[e], 0), N-1);
            d = min(max(ei[(size_t)E + e], 0), N-1);
        } else { s = d = e - E; }
        unsigned p = atomicAdd(&cursor[d], 1u);
        rec[p] = make_int2(s, d);
    }
}

// ---- edge kernel: contiguous per-lg quarters; interior runs -> PLAIN stores --------------
__global__ __launch_bounds__(256, 3) void edge_mfma_kernel(
    const int2* __restrict__ rec, const float* __restrict__ pos,
    const unsigned short* __restrict__ ADb, const unsigned short* __restrict__ ASb,
    const unsigned short* __restrict__ xvb,
    const float* __restrict__ pW1, const float* __restrict__ pb1,
    const float* __restrict__ pW2, const float* __restrict__ pb2,
    const float* __restrict__ aW1, const float* __restrict__ ab1,
    const float* __restrict__ aW2, const float* __restrict__ ab2,
    float* __restrict__ esum, unsigned* __restrict__ outb,
    int N, int E)
{
    const int tid = threadIdx.x;
    const int lane = tid & 63;
    const int wid  = tid >> 6;
    const int lm = lane & 15;
    const int lg = lane >> 4;

    __shared__ __align__(16) unsigned short swt[3][64 * WPAD];
    __shared__ __align__(16) unsigned short tb[4][16 * WPAD];
    __shared__ unsigned spw[2][64];

    {
        const float* Wsrc[3] = {pW2, aW1, aW2};
        #pragma unroll
        for (int w = 0; w < 3; ++w)
            for (int idx = tid; idx < 4096; idx += 256) {
                int k = idx >> 6, o = idx & 63;
                swt[w][o*WPAD + k] = f2b(Wsrc[w][idx]);
            }
        if (tid < 64) {
            spw[0][tid] = (unsigned)f2b(pW1[tid])     | ((unsigned)f2b(pW1[64+tid]) << 16);
            spw[1][tid] = (unsigned)f2b(pW1[128+tid]) | ((unsigned)f2b(pb1[tid])    << 16);
        }
    }
    __syncthreads();

    float pb2v[4], ab1v[4], ab2v[4];
    #pragma unroll
    for (int tt = 0; tt < 4; ++tt) {
        pb2v[tt] = pb2[lm + 16*tt];
        ab1v[tt] = ab1[lm + 16*tt];
        ab2v[tt] = ab2[lm + 16*tt];
    }

    unsigned short* tbw = tb[wid];
    const int total = E + N;
    const int ntiles = (total + 15) >> 4;
    const int nwaves = gridDim.x * 4;
    const int tpw = (ntiles + nwaves - 1) / nwaves;
    const int gw = blockIdx.x * 4 + wid;
    const int t0 = min(gw * tpw, ntiles);
    const int t1 = min(t0 + tpw, ntiles);
    if (t0 >= t1) return;
    const int nstep = t1 - t0;
    const int qlen  = 4 * nstep;
    const int rbase = t0 << 4;
    const int pq = rbase + (lm >> 2)*qlen + (lm & 3);
    const int gq = rbase + lg*qlen;

    int   curD = -1;
    bool  firstF = true;
    float sA[4]  = {0.f, 0.f, 0.f, 0.f};
    float mxA[4] = {-INFINITY, -INFINITY, -INFINITY, -INFINITY};

    int2 rp_n, rg_n0, rg_n1, rg_n2, rg_n3;
    rp_n  = rec[min(pq, total-1)];
    rg_n0 = rec[min(gq+0, total-1)];
    rg_n1 = rec[min(gq+1, total-1)];
    rg_n2 = rec[min(gq+2, total-1)];
    rg_n3 = rec[min(gq+3, total-1)];

    for (int step = 0; step < nstep; ++step) {
        const int2 rp = rp_n;
        int sg[4], dg[4];
        sg[0] = rg_n0.x; dg[0] = rg_n0.y;
        sg[1] = rg_n1.x; dg[1] = rg_n1.y;
        sg[2] = rg_n2.x; dg[2] = rg_n2.y;
        sg[3] = rg_n3.x; dg[3] = rg_n3.y;
        int actm = 0;
        #pragma unroll
        for (int r = 0; r < 4; ++r)
            if (gq + step*4 + r < total) actm |= (1 << r);

        float q0 = pos[(size_t)rp.y*3+0] - pos[(size_t)rp.x*3+0];
        float q1 = pos[(size_t)rp.y*3+1] - pos[(size_t)rp.x*3+1];
        float q2 = pos[(size_t)rp.y*3+2] - pos[(size_t)rp.x*3+2];

        float gd[4][4], gxv[4][4];
        #pragma unroll
        for (int r = 0; r < 4; ++r) {
            const ushort4 a4 = *(const ushort4*)&ADb[(size_t)dg[r]*CC + lm*4];
            const ushort4 s4 = *(const ushort4*)&ASb[(size_t)sg[r]*CC + lm*4];
            const ushort4 x4 = *(const ushort4*)&xvb[(size_t)sg[r]*CC + lm*4];
            gd[r][0] = b2f(a4.x) - b2f(s4.x);
            gd[r][1] = b2f(a4.y) - b2f(s4.y);
            gd[r][2] = b2f(a4.z) - b2f(s4.z);
            gd[r][3] = b2f(a4.w) - b2f(s4.w);
            gxv[r][0] = b2f(x4.x); gxv[r][1] = b2f(x4.y);
            gxv[r][2] = b2f(x4.z); gxv[r][3] = b2f(x4.w);
        }

        if (step + 1 < nstep) {
            const int pn = pq + (step+1)*4;
            const int gn = gq + (step+1)*4;
            rp_n  = rec[min(pn,   total-1)];
            rg_n0 = rec[min(gn+0, total-1)];
            rg_n1 = rec[min(gn+1, total-1)];
            rg_n2 = rec[min(gn+2, total-1)];
            rg_n3 = rec[min(gn+3, total-1)];
        }

        s16x8 Alo, Ahi;
        #pragma unroll
        for (int j = 0; j < 16; ++j) {
            int k = lg*8 + (j & 7) + 32*(j >> 3);
            unsigned wa = ((volatile unsigned*)spw[0])[k];
            unsigned wb = ((volatile unsigned*)spw[1])[k];
            float w0 = __uint_as_float(wa << 16);
            float w1 = __uint_as_float(wa & 0xFFFF0000u);
            float w2 = __uint_as_float(wb << 16);
            float bb = __uint_as_float(wb & 0xFFFF0000u);
            float v = fmaxf(fmaf(q0, w0, fmaf(q1, w1, fmaf(q2, w2, bb))), 0.f);
            short b = (short)f2b(v);
            if (j < 8) Alo[j] = b; else Ahi[j-8] = b;
        }

        f32x4 dlt[4];
        #pragma unroll
        for (int tt = 0; tt < 4; ++tt) {
            s16x8 b0 = *(const s16x8*)&swt[0][(lm + 16*tt)*WPAD + lg*8];
            s16x8 b1 = *(const s16x8*)&swt[0][(lm + 16*tt)*WPAD + 32 + lg*8];
            f32x4 z = {0.f, 0.f, 0.f, 0.f};
            z = __builtin_amdgcn_mfma_f32_16x16x32_bf16(Alo, b0, z, 0, 0, 0);
            z = __builtin_amdgcn_mfma_f32_16x16x32_bf16(Ahi, b1, z, 0, 0, 0);
            #pragma unroll
            for (int r = 0; r < 4; ++r) dlt[tt][r] = fmaxf(z[r] + pb2v[tt], 0.f);
        }

        #pragma unroll
        for (int tt = 0; tt < 4; ++tt)
            #pragma unroll
            for (int r = 0; r < 4; ++r)
                tbw[(lg*4+r)*WPAD + lm + 16*tt] = f2b(dlt[tt][r]);
        __builtin_amdgcn_wave_barrier();
        s16x8 Dlo = *(const s16x8*)&tbw[lm*WPAD + lg*8];
        s16x8 Dhi = *(const s16x8*)&tbw[lm*WPAD + 32 + lg*8];
        __builtin_amdgcn_wave_barrier();

        #pragma unroll
        for (int tt = 0; tt < 4; ++tt) {
            s16x8 b0 = *(const s16x8*)&swt[1][(lm + 16*tt)*WPAD + lg*8];
            s16x8 b1 = *(const s16x8*)&swt[1][(lm + 16*tt)*WPAD + 32 + lg*8];
            f32x4 z = {0.f, 0.f, 0.f, 0.f};
            z = __builtin_amdgcn_mfma_f32_16x16x32_bf16(Dlo, b0, z, 0, 0, 0);
            z = __builtin_amdgcn_mfma_f32_16x16x32_bf16(Dhi, b1, z, 0, 0, 0);
            #pragma unroll
            for (int r = 0; r < 4; ++r) {
                float v = fmaxf(z[r] + gd[r][tt] + ab1v[tt], 0.f);
                tbw[(lg*4+r)*WPAD + lm + 16*tt] = f2b(v);
            }
        }
        __builtin_amdgcn_wave_barrier();
        s16x8 Hlo = *(const s16x8*)&tbw[lm*WPAD + lg*8];
        s16x8 Hhi = *(const s16x8*)&tbw[lm*WPAD + 32 + lg*8];
        __builtin_amdgcn_wave_barrier();

        f32x4 zz[4];
        #pragma unroll
        for (int tt = 0; tt < 4; ++tt) {
            s16x8 b0 = *(const s16x8*)&swt[2][(lm + 16*tt)*WPAD + lg*8];
            s16x8 b1 = *(const s16x8*)&swt[2][(lm + 16*tt)*WPAD + 32 + lg*8];
            f32x4 z = {0.f, 0.f, 0.f, 0.f};
            z = __builtin_amdgcn_mfma_f32_16x16x32_bf16(Hlo, b0, z, 0, 0, 0);
            zz[tt] = __builtin_amdgcn_mfma_f32_16x16x32_bf16(Hhi, b1, z, 0, 0, 0);
        }

        #pragma unroll
        for (int r = 0; r < 4; ++r) {
            if (!(actm & (1 << r))) continue;
            if (dg[r] != curD) {
                if (curD >= 0) {
                    if (firstF) {
                        #pragma unroll
                        for (int tt = 0; tt < 4; ++tt) {
                            size_t off = (size_t)curD*CC + lm + 16*tt;
                            atomicAdd(&esum[off], sA[tt]);
                            atomicMax(&outb[off], fmono(mxA[tt]));
                        }
                    } else {
                        #pragma unroll
                        for (int tt = 0; tt < 4; ++tt) {
                            size_t off = (size_t)curD*CC + lm + 16*tt;
                            esum[off] = sA[tt];
                            outb[off] = fmono(mxA[tt]);
                        }
                    }
                    firstF = false;
                }
                curD = dg[r];
                #pragma unroll
                for (int tt = 0; tt < 4; ++tt) { sA[tt] = 0.f; mxA[tt] = -INFINITY; }
            }
            #pragma unroll
            for (int tt = 0; tt < 4; ++tt) {
                float a  = fmaxf(zz[tt][r] + ab2v[tt], 0.f);
                float ee = __expf(a);
                float m  = ee * (gxv[r][tt] + dlt[tt][r]);
                sA[tt] += ee;
                mxA[tt] = fmaxf(mxA[tt], m);
            }
        }
    }

    if (curD >= 0) {
        #pragma unroll
        for (int tt = 0; tt < 4; ++tt) {
            size_t off = (size_t)curD*CC + lm + 16*tt;
            atomicAdd(&esum[off], sA[tt]);
            atomicMax(&outb[off], fmono(mxA[tt]));
        }
    }
}

// ---- output kernel (MFMA): out = relu((decode(outb)/esum) @ W_out^T + b_out) -------------
__global__ __launch_bounds__(256, 2) void out_mfma_kernel(
    const unsigned* outb_in,            // aliases out -- no restrict
    const float* __restrict__ esum,
    const float* __restrict__ W_out, const float* __restrict__ b_out,
    float* out, int N)
{
    const int tid = threadIdx.x;
    const int lane = tid & 63;
    const int wid  = tid >> 6;
    const int lm = lane & 15;
    const int lg = lane >> 4;

    __shared__ __align__(16) unsigned short swt[64 * WPAD];
    for (int idx = tid; idx < 4096; idx += 256) {
        int o = idx >> 6, k = idx & 63;
        swt[o*WPAD + k] = f2b(W_out[(size_t)o*64 + k]);
    }
    __syncthreads();

    const int wbase = blockIdx.x * 64 + wid * 16;
    if (wbase >= N) return;

    const int row = min(wbase + lm, N-1);
    const unsigned* up = &outb_in[(size_t)row*CC];
    const float*    ep = &esum[(size_t)row*CC];
    s16x8 Alo, Ahi;
    #pragma unroll
    for (int half = 0; half < 2; ++half) {
        int kb = half*32 + lg*8;
        uint4  u0 = *(const uint4*)&up[kb];
        uint4  u1 = *(const uint4*)&up[kb+4];
        float4 e0 = *(const float4*)&ep[kb];
        float4 e1 = *(const float4*)&ep[kb+4];
        unsigned uu[8] = {u0.x,u0.y,u0.z,u0.w,u1.x,u1.y,u1.z,u1.w};
        float    ee[8] = {e0.x,e0.y,e0.z,e0.w,e1.x,e1.y,e1.z,e1.w};
        #pragma unroll
        for (int j = 0; j < 8; ++j) {
            unsigned u = uu[j];
            u = (u >> 31) ? (u ^ 0x80000000u) : ~u;    // inverse of fmono
            float v = __fdividef(__uint_as_float(u), ee[j]);
            if (half == 0) Alo[j] = (short)f2b(v); else Ahi[j] = (short)f2b(v);
        }
    }

    f32x4 zz[4];
    #pragma unroll
    for (int tt = 0; tt < 4; ++tt) {
        s16x8 b0 = *(const s16x8*)&swt[(lm + 16*tt)*WPAD + lg*8];
        s16x8 b1 = *(const s16x8*)&swt[(lm + 16*tt)*WPAD + 32 + lg*8];
        f32x4 z = {0.f, 0.f, 0.f, 0.f};
        z = __builtin_amdgcn_mfma_f32_16x16x32_bf16(Alo, b0, z, 0, 0, 0);
        zz[tt] = __builtin_amdgcn_mfma_f32_16x16x32_bf16(Ahi, b1, z, 0, 0, 0);
    }
    float bo[4];
    #pragma unroll
    for (int tt = 0; tt < 4; ++tt) bo[tt] = b_out[lm + 16*tt];

    #pragma unroll
    for (int r = 0; r < 4; ++r) {
        int n = wbase + lg*4 + r;
        if (n < N) {
            #pragma unroll
            for (int tt = 0; tt < 4; ++tt)
                out[(size_t)n*CC + lm + 16*tt] = fmaxf(zz[tt][r] + bo[tt], 0.f);
        }
    }
}

extern "C" void kernel_launch(void* const* d_in, const int* in_sizes, int n_in,
                              void* d_out, int out_size, void* d_ws, size_t ws_size,
                              hipStream_t stream)
{
    const float* x     = (const float*)d_in[0];
    const float* pos   = (const float*)d_in[1];
    const int*   ei    = (const int*)d_in[2];
    const float* W_in  = (const float*)d_in[3];
    const float* b_in  = (const float*)d_in[4];
    const float* W_out = (const float*)d_in[5];
    const float* b_out = (const float*)d_in[6];
    const float* W_lin = (const float*)d_in[7];
    const float* W_src = (const float*)d_in[8];
    const float* W_dst = (const float*)d_in[9];
    const float* pW1   = (const float*)d_in[10];
    const float* pb1   = (const float*)d_in[11];
    const float* pW2   = (const float*)d_in[12];
    const float* pb2   = (const float*)d_in[13];
    const float* aW1   = (const float*)d_in[14];
    const float* ab1   = (const float*)d_in[15];
    const float* aW2   = (const float*)d_in[16];
    const float* ab2   = (const float*)d_in[17];

    const int N = in_sizes[0] / CC;
    const int E = in_sizes[2] / 2;
    const size_t nc = (size_t)N * CC;

    char* wsb = (char*)d_ws;
    unsigned short* ASb = (unsigned short*)wsb;        // nc * 2B
    unsigned short* ADb = ASb + nc;                    // nc * 2B
    unsigned short* xvb = ADb + nc;                    // nc * 2B
    float* esum = (float*)(((size_t)(xvb + nc) + 15) & ~(size_t)15);   // nc * 4B
    unsigned* cnt       = (unsigned*)(esum + nc);
    unsigned* chunk_off = cnt + N;
    unsigned* cursor    = chunk_off + N;
    unsigned* partials  = cursor + N;                  // 1024 entries
    size_t rec_off = ((size_t)((char*)(partials + 1024) - wsb) + 15) & ~(size_t)15;
    int2* rec = (int2*)(wsb + rec_off);
    unsigned* outb = (unsigned*)d_out;

    hipMemsetAsync(esum, 0, nc*sizeof(float), stream);
    hipMemsetAsync(outb, 0, nc*sizeof(float), stream);
    hipMemsetAsync(cnt, 0, (size_t)N*sizeof(unsigned), stream);

    const int nblk = (N + 63) / 64;
    node_mfma_kernel<<<nblk, 256, 0, stream>>>(x, W_in, b_in, W_src, W_dst, W_lin, aW1,
                                               ASb, ADb, xvb, ei, cnt, N, E);
    const int nchunks = (N + 1023) / 1024;
    scan1_kernel<<<nchunks, SCAN_T, 0, stream>>>(cnt, chunk_off, partials, N);
    scan2_kernel<<<1, 1024, 0, stream>>>(partials, nchunks);
    scan3_kernel<<<(N + 255)/256, 256, 0, stream>>>(chunk_off, partials, cursor, N);
    scatter_kernel<<<2048, 256, 0, stream>>>(ei, cursor, rec, N, E);
    edge_mfma_kernel<<<2048, 256, 0, stream>>>(rec, pos, ADb, ASb, xvb,
                                               pW1, pb1, pW2, pb2, aW1, ab1, aW2, ab2,
                                               esum, outb, N, E);
    out_mfma_kernel<<<nblk, 256, 0, stream>>>(outb, esum, W_out, b_out, (float*)d_out, N);
}

// Round 19
// 469.418 us; speedup vs baseline: 1.1015x; 1.1015x over previous
//
#include <hip/hip_runtime.h>
#include <hip/hip_bf16.h>

#define CC 64
#define WPAD 72

typedef __attribute__((ext_vector_type(8))) short s16x8;
typedef __attribute__((ext_vector_type(4))) float f32x4;

__device__ __forceinline__ unsigned short f2b(float f) {   // f32 -> bf16 via HW cvt (RNE)
    __bf16 h = (__bf16)f;
    return __builtin_bit_cast(unsigned short, h);
}
__device__ __forceinline__ float b2f(unsigned short b) {   // bf16 bits -> f32
    return __uint_as_float((unsigned)b << 16);
}
__device__ __forceinline__ unsigned fmono(float f) {       // order-preserving f32->u32
    unsigned u = __float_as_uint(f);
    return u ^ ((unsigned)((int)u >> 31) | 0x80000000u);
}

// ---- node kernel (MFMA) + fused dst-histogram (identity k-perm, WPAD=72) -----------------
__global__ __launch_bounds__(256, 2) void node_mfma_kernel(
    const float* __restrict__ x,
    const float* __restrict__ W_in, const float* __restrict__ b_in,
    const float* __restrict__ W_src, const float* __restrict__ W_dst,
    const float* __restrict__ W_lin, const float* __restrict__ aW1,
    unsigned short* __restrict__ ASb, unsigned short* __restrict__ ADb,
    unsigned short* __restrict__ xvb,
    const int* __restrict__ ei, unsigned* __restrict__ cnt, int N, int E)
{
    const int tid = threadIdx.x;
    const int lane = tid & 63;
    const int wid  = tid >> 6;
    const int lm = lane & 15;
    const int lg = lane >> 4;

    __shared__ __align__(16) unsigned short swt[5][64 * WPAD];
    __shared__ __align__(16) unsigned short tb[4][16 * WPAD];

    {
        const float* Wr[4] = {W_in, W_src, W_dst, W_lin};
        #pragma unroll
        for (int w = 0; w < 4; ++w)
            for (int idx = tid; idx < 4096; idx += 256) {
                int o = idx >> 6, k = idx & 63;
                swt[w][o*WPAD + k] = f2b(Wr[w][(size_t)o*64 + k]);
            }
        for (int idx = tid; idx < 4096; idx += 256) {
            int k = idx >> 6, o = idx & 63;
            swt[4][o*WPAD + k] = f2b(aW1[idx]);     // aW1[k][o]
        }
    }
    __syncthreads();

    const int wbase = blockIdx.x * 64 + wid * 16;
    unsigned short* tbw = tb[wid];

    if (wbase < N) {
        float bin[4];
        #pragma unroll
        for (int tt = 0; tt < 4; ++tt) bin[tt] = b_in[lm + 16*tt];

        const int xrow = min(wbase + lm, N-1);
        const float* xp = &x[(size_t)xrow*CC];
        float4 a0 = *(const float4*)&xp[lg*8];
        float4 a1 = *(const float4*)&xp[lg*8 + 4];
        float4 a2 = *(const float4*)&xp[32 + lg*8];
        float4 a3 = *(const float4*)&xp[32 + lg*8 + 4];
        s16x8 Xlo, Xhi;
        Xlo[0]=(short)f2b(a0.x); Xlo[1]=(short)f2b(a0.y); Xlo[2]=(short)f2b(a0.z); Xlo[3]=(short)f2b(a0.w);
        Xlo[4]=(short)f2b(a1.x); Xlo[5]=(short)f2b(a1.y); Xlo[6]=(short)f2b(a1.z); Xlo[7]=(short)f2b(a1.w);
        Xhi[0]=(short)f2b(a2.x); Xhi[1]=(short)f2b(a2.y); Xhi[2]=(short)f2b(a2.z); Xhi[3]=(short)f2b(a2.w);
        Xhi[4]=(short)f2b(a3.x); Xhi[5]=(short)f2b(a3.y); Xhi[6]=(short)f2b(a3.z); Xhi[7]=(short)f2b(a3.w);

        auto mm = [&](s16x8 alo, s16x8 ahi, int w, f32x4* zz) {
            #pragma unroll
            for (int tt = 0; tt < 4; ++tt) {
                s16x8 b0 = *(const s16x8*)&swt[w][(lm + 16*tt)*WPAD + lg*8];
                s16x8 b1 = *(const s16x8*)&swt[w][(lm + 16*tt)*WPAD + 32 + lg*8];
                f32x4 z = {0.f, 0.f, 0.f, 0.f};
                z = __builtin_amdgcn_mfma_f32_16x16x32_bf16(alo, b0, z, 0, 0, 0);
                zz[tt] = __builtin_amdgcn_mfma_f32_16x16x32_bf16(ahi, b1, z, 0, 0, 0);
            }
        };
        auto transpose = [&](const f32x4* zz, s16x8& olo, s16x8& ohi) {
            #pragma unroll
            for (int tt = 0; tt < 4; ++tt)
                #pragma unroll
                for (int r = 0; r < 4; ++r)
                    tbw[(lg*4+r)*WPAD + lm + 16*tt] = f2b(zz[tt][r]);
            __builtin_amdgcn_wave_barrier();
            olo = *(const s16x8*)&tbw[lm*WPAD + lg*8];
            ohi = *(const s16x8*)&tbw[lm*WPAD + 32 + lg*8];
            __builtin_amdgcn_wave_barrier();
        };
        auto store_perm = [&](const f32x4* zz, unsigned short* out) {
            #pragma unroll
            for (int r = 0; r < 4; ++r) {
                int n = wbase + lg*4 + r;
                if (n < N) {
                    ushort4 v = make_ushort4(f2b(zz[0][r]), f2b(zz[1][r]),
                                             f2b(zz[2][r]), f2b(zz[3][r]));
                    *(ushort4*)&out[(size_t)n*CC + lm*4] = v;
                }
            }
        };

        f32x4 zh[4], zt[4], zo[4];
        mm(Xlo, Xhi, 0, zh);
        #pragma unroll
        for (int tt = 0; tt < 4; ++tt)
            #pragma unroll
            for (int r = 0; r < 4; ++r)
                zh[tt][r] = fmaxf(zh[tt][r] + bin[tt], 0.f);
        s16x8 Hlo, Hhi;
        transpose(zh, Hlo, Hhi);

        mm(Hlo, Hhi, 1, zt);
        { s16x8 Tlo, Thi; transpose(zt, Tlo, Thi); mm(Tlo, Thi, 4, zo); }
        store_perm(zo, ASb);

        mm(Hlo, Hhi, 2, zt);
        { s16x8 Tlo, Thi; transpose(zt, Tlo, Thi); mm(Tlo, Thi, 4, zo); }
        store_perm(zo, ADb);

        mm(Hlo, Hhi, 3, zo);
        store_perm(zo, xvb);
    }

    const int total = E + N;
    for (int e = blockIdx.x*256 + tid; e < total; e += gridDim.x*256) {
        int d = (e < E) ? min(max(ei[(size_t)E + e], 0), N-1) : (e - E);
        atomicAdd(&cnt[d], 1u);
    }
}

// ---- exclusive scan (3 kernels) + scatter ------------------------------------------------
#define SCAN_T 256
__global__ __launch_bounds__(SCAN_T) void scan1_kernel(
    const unsigned* __restrict__ cnt, unsigned* __restrict__ chunk_off,
    unsigned* __restrict__ partials, int n)
{
    __shared__ unsigned sh[SCAN_T];
    const int t = threadIdx.x, b0 = blockIdx.x * (SCAN_T*4);
    unsigned v[4], s = 0;
    #pragma unroll
    for (int i = 0; i < 4; ++i) {
        int idx = b0 + t*4 + i;
        v[i] = (idx < n) ? cnt[idx] : 0u;
        s += v[i];
    }
    sh[t] = s; __syncthreads();
    for (int d = 1; d < SCAN_T; d <<= 1) {
        unsigned xv = (t >= d) ? sh[t-d] : 0u;
        __syncthreads();
        sh[t] += xv;
        __syncthreads();
    }
    unsigned run = (t > 0) ? sh[t-1] : 0u;
    #pragma unroll
    for (int i = 0; i < 4; ++i) {
        int idx = b0 + t*4 + i;
        if (idx < n) chunk_off[idx] = run;
        run += v[i];
    }
    if (t == SCAN_T-1) partials[blockIdx.x] = sh[SCAN_T-1];
}

__global__ __launch_bounds__(1024) void scan2_kernel(unsigned* __restrict__ partials, int nb)
{
    __shared__ unsigned sh[1024];
    const int t = threadIdx.x;
    sh[t] = (t < nb) ? partials[t] : 0u; __syncthreads();
    for (int d = 1; d < 1024; d <<= 1) {
        unsigned xv = (t >= d) ? sh[t-d] : 0u;
        __syncthreads();
        sh[t] += xv;
        __syncthreads();
    }
    if (t < nb) partials[t] = (t > 0) ? sh[t-1] : 0u;
}

__global__ __launch_bounds__(256) void scan3_kernel(
    const unsigned* __restrict__ chunk_off, const unsigned* __restrict__ partials,
    unsigned* __restrict__ cursor, int n)
{
    int i = blockIdx.x*256 + threadIdx.x;
    if (i < n) cursor[i] = chunk_off[i] + partials[i >> 10];
}

__global__ __launch_bounds__(256) void scatter_kernel(
    const int* __restrict__ ei, unsigned* __restrict__ cursor,
    int2* __restrict__ rec, int N, int E)
{
    const int total = E + N;
    for (int e = blockIdx.x*256 + threadIdx.x; e < total; e += gridDim.x*256) {
        int s, d;
        if (e < E) {
            s = min(max(ei[e], 0), N-1);
            d = min(max(ei[(size_t)E + e], 0), N-1);
        } else { s = d = e - E; }
        unsigned p = atomicAdd(&cursor[d], 1u);
        rec[p] = make_int2(s, d);
    }
}

// ---- edge kernel: permuted-k (p = 4*col + tt) -> packed b64 transpose writes -------------
// Channel at k-position p is c(p) = (p>>2) + 16*(p&3); A and B both use this mapping, so
// the MFMA sum over positions equals the sum over channels. Interior-run plain stores.
__global__ __launch_bounds__(256, 3) void edge_mfma_kernel(
    const int2* __restrict__ rec, const float* __restrict__ pos,
    const unsigned short* __restrict__ ADb, const unsigned short* __restrict__ ASb,
    const unsigned short* __restrict__ xvb,
    const float* __restrict__ pW1, const float* __restrict__ pb1,
    const float* __restrict__ pW2, const float* __restrict__ pb2,
    const float* __restrict__ aW1, const float* __restrict__ ab1,
    const float* __restrict__ aW2, const float* __restrict__ ab2,
    float* __restrict__ esum, unsigned* __restrict__ outb,
    int N, int E)
{
    const int tid = threadIdx.x;
    const int lane = tid & 63;
    const int wid  = tid >> 6;
    const int lm = lane & 15;
    const int lg = lane >> 4;

    __shared__ __align__(16) unsigned short swt[3][64 * WPAD];
    __shared__ __align__(16) unsigned short tb[4][16 * WPAD];
    __shared__ unsigned spw[2][64];

    {
        const float* Wsrc[3] = {pW2, aW1, aW2};
        #pragma unroll
        for (int w = 0; w < 3; ++w)
            for (int idx = tid; idx < 4096; idx += 256) {
                int p = idx >> 6, o = idx & 63;
                int c = (p >> 2) + 16*(p & 3);
                swt[w][o*WPAD + p] = f2b(Wsrc[w][(size_t)c*64 + o]);
            }
        if (tid < 64) {
            spw[0][tid] = (unsigned)f2b(pW1[tid])     | ((unsigned)f2b(pW1[64+tid]) << 16);
            spw[1][tid] = (unsigned)f2b(pW1[128+tid]) | ((unsigned)f2b(pb1[tid])    << 16);
        }
    }
    __syncthreads();

    float pb2v[4], ab1v[4], ab2v[4];
    #pragma unroll
    for (int tt = 0; tt < 4; ++tt) {
        pb2v[tt] = pb2[lm + 16*tt];
        ab1v[tt] = ab1[lm + 16*tt];
        ab2v[tt] = ab2[lm + 16*tt];
    }

    unsigned short* tbw = tb[wid];
    const int total = E + N;
    const int ntiles = (total + 15) >> 4;
    const int nwaves = gridDim.x * 4;
    const int tpw = (ntiles + nwaves - 1) / nwaves;
    const int gw = blockIdx.x * 4 + wid;
    const int t0 = min(gw * tpw, ntiles);
    const int t1 = min(t0 + tpw, ntiles);
    if (t0 >= t1) return;
    const int nstep = t1 - t0;
    const int qlen  = 4 * nstep;
    const int rbase = t0 << 4;
    const int pq = rbase + (lm >> 2)*qlen + (lm & 3);
    const int gq = rbase + lg*qlen;

    int   curD = -1;
    bool  firstF = true;
    float sA[4]  = {0.f, 0.f, 0.f, 0.f};
    float mxA[4] = {-INFINITY, -INFINITY, -INFINITY, -INFINITY};

    int2 rp_n, rg_n0, rg_n1, rg_n2, rg_n3;
    rp_n  = rec[min(pq, total-1)];
    rg_n0 = rec[min(gq+0, total-1)];
    rg_n1 = rec[min(gq+1, total-1)];
    rg_n2 = rec[min(gq+2, total-1)];
    rg_n3 = rec[min(gq+3, total-1)];

    for (int step = 0; step < nstep; ++step) {
        const int2 rp = rp_n;
        int sg[4], dg[4];
        sg[0] = rg_n0.x; dg[0] = rg_n0.y;
        sg[1] = rg_n1.x; dg[1] = rg_n1.y;
        sg[2] = rg_n2.x; dg[2] = rg_n2.y;
        sg[3] = rg_n3.x; dg[3] = rg_n3.y;
        int actm = 0;
        #pragma unroll
        for (int r = 0; r < 4; ++r)
            if (gq + step*4 + r < total) actm |= (1 << r);

        float q0 = pos[(size_t)rp.y*3+0] - pos[(size_t)rp.x*3+0];
        float q1 = pos[(size_t)rp.y*3+1] - pos[(size_t)rp.x*3+1];
        float q2 = pos[(size_t)rp.y*3+2] - pos[(size_t)rp.x*3+2];

        float gd[4][4], gxv[4][4];
        #pragma unroll
        for (int r = 0; r < 4; ++r) {
            const ushort4 a4 = *(const ushort4*)&ADb[(size_t)dg[r]*CC + lm*4];
            const ushort4 s4 = *(const ushort4*)&ASb[(size_t)sg[r]*CC + lm*4];
            const ushort4 x4 = *(const ushort4*)&xvb[(size_t)sg[r]*CC + lm*4];
            gd[r][0] = b2f(a4.x) - b2f(s4.x);
            gd[r][1] = b2f(a4.y) - b2f(s4.y);
            gd[r][2] = b2f(a4.z) - b2f(s4.z);
            gd[r][3] = b2f(a4.w) - b2f(s4.w);
            gxv[r][0] = b2f(x4.x); gxv[r][1] = b2f(x4.y);
            gxv[r][2] = b2f(x4.z); gxv[r][3] = b2f(x4.w);
        }

        if (step + 1 < nstep) {
            const int pn = pq + (step+1)*4;
            const int gn = gq + (step+1)*4;
            rp_n  = rec[min(pn,   total-1)];
            rg_n0 = rec[min(gn+0, total-1)];
            rg_n1 = rec[min(gn+1, total-1)];
            rg_n2 = rec[min(gn+2, total-1)];
            rg_n3 = rec[min(gn+3, total-1)];
        }

        // ---- p1 = relu(pdiff@pW1 + pb1) in A-frag layout (permuted k) ----
        s16x8 Alo, Ahi;
        #pragma unroll
        for (int j = 0; j < 16; ++j) {
            int p = lg*8 + (j & 7) + 32*(j >> 3);
            int k = (p >> 2) + 16*(p & 3);
            unsigned wa = ((volatile unsigned*)spw[0])[k];
            unsigned wb = ((volatile unsigned*)spw[1])[k];
            float w0 = __uint_as_float(wa << 16);
            float w1 = __uint_as_float(wa & 0xFFFF0000u);
            float w2 = __uint_as_float(wb << 16);
            float bb = __uint_as_float(wb & 0xFFFF0000u);
            float v = fmaxf(fmaf(q0, w0, fmaf(q1, w1, fmaf(q2, w2, bb))), 0.f);
            short b = (short)f2b(v);
            if (j < 8) Alo[j] = b; else Ahi[j-8] = b;
        }

        // ---- layer 1: delta = relu(p1 @ pW2 + pb2) ----
        f32x4 dlt[4];
        #pragma unroll
        for (int tt = 0; tt < 4; ++tt) {
            s16x8 b0 = *(const s16x8*)&swt[0][(lm + 16*tt)*WPAD + lg*8];
            s16x8 b1 = *(const s16x8*)&swt[0][(lm + 16*tt)*WPAD + 32 + lg*8];
            f32x4 z = {0.f, 0.f, 0.f, 0.f};
            z = __builtin_amdgcn_mfma_f32_16x16x32_bf16(Alo, b0, z, 0, 0, 0);
            z = __builtin_amdgcn_mfma_f32_16x16x32_bf16(Ahi, b1, z, 0, 0, 0);
            #pragma unroll
            for (int r = 0; r < 4; ++r) dlt[tt][r] = fmaxf(z[r] + pb2v[tt], 0.f);
        }

        // ---- transpose 1: packed b64 writes (position 4*lm+tt == channel lm+16tt) ----
        #pragma unroll
        for (int r = 0; r < 4; ++r) {
            ushort4 v = make_ushort4(f2b(dlt[0][r]), f2b(dlt[1][r]),
                                     f2b(dlt[2][r]), f2b(dlt[3][r]));
            *(ushort4*)&tbw[(lg*4+r)*WPAD + 4*lm] = v;
        }
        __builtin_amdgcn_wave_barrier();
        s16x8 Dlo = *(const s16x8*)&tbw[lm*WPAD + lg*8];
        s16x8 Dhi = *(const s16x8*)&tbw[lm*WPAD + 32 + lg*8];
        __builtin_amdgcn_wave_barrier();

        // ---- layer 2: h1 = relu(gd + delta@aW1 + ab1) -> packed transpose 2 ----
        float h1v[4][4];
        #pragma unroll
        for (int tt = 0; tt < 4; ++tt) {
            s16x8 b0 = *(const s16x8*)&swt[1][(lm + 16*tt)*WPAD + lg*8];
            s16x8 b1 = *(const s16x8*)&swt[1][(lm + 16*tt)*WPAD + 32 + lg*8];
            f32x4 z = {0.f, 0.f, 0.f, 0.f};
            z = __builtin_amdgcn_mfma_f32_16x16x32_bf16(Dlo, b0, z, 0, 0, 0);
            z = __builtin_amdgcn_mfma_f32_16x16x32_bf16(Dhi, b1, z, 0, 0, 0);
            #pragma unroll
            for (int r = 0; r < 4; ++r)
                h1v[tt][r] = fmaxf(z[r] + gd[r][tt] + ab1v[tt], 0.f);
        }
        #pragma unroll
        for (int r = 0; r < 4; ++r) {
            ushort4 v = make_ushort4(f2b(h1v[0][r]), f2b(h1v[1][r]),
                                     f2b(h1v[2][r]), f2b(h1v[3][r]));
            *(ushort4*)&tbw[(lg*4+r)*WPAD + 4*lm] = v;
        }
        __builtin_amdgcn_wave_barrier();
        s16x8 Hlo = *(const s16x8*)&tbw[lm*WPAD + lg*8];
        s16x8 Hhi = *(const s16x8*)&tbw[lm*WPAD + 32 + lg*8];
        __builtin_amdgcn_wave_barrier();

        // ---- layer 3 + run-carried aggregation ----
        f32x4 zz[4];
        #pragma unroll
        for (int tt = 0; tt < 4; ++tt) {
            s16x8 b0 = *(const s16x8*)&swt[2][(lm + 16*tt)*WPAD + lg*8];
            s16x8 b1 = *(const s16x8*)&swt[2][(lm + 16*tt)*WPAD + 32 + lg*8];
            f32x4 z = {0.f, 0.f, 0.f, 0.f};
            z = __builtin_amdgcn_mfma_f32_16x16x32_bf16(Hlo, b0, z, 0, 0, 0);
            zz[tt] = __builtin_amdgcn_mfma_f32_16x16x32_bf16(Hhi, b1, z, 0, 0, 0);
        }

        #pragma unroll
        for (int r = 0; r < 4; ++r) {
            if (!(actm & (1 << r))) continue;
            if (dg[r] != curD) {
                if (curD >= 0) {
                    if (firstF) {
                        #pragma unroll
                        for (int tt = 0; tt < 4; ++tt) {
                            size_t off = (size_t)curD*CC + lm + 16*tt;
                            atomicAdd(&esum[off], sA[tt]);
                            atomicMax(&outb[off], fmono(mxA[tt]));
                        }
                    } else {
                        #pragma unroll
                        for (int tt = 0; tt < 4; ++tt) {
                            size_t off = (size_t)curD*CC + lm + 16*tt;
                            esum[off] = sA[tt];
                            outb[off] = fmono(mxA[tt]);
                        }
                    }
                    firstF = false;
                }
                curD = dg[r];
                #pragma unroll
                for (int tt = 0; tt < 4; ++tt) { sA[tt] = 0.f; mxA[tt] = -INFINITY; }
            }
            #pragma unroll
            for (int tt = 0; tt < 4; ++tt) {
                float a  = fmaxf(zz[tt][r] + ab2v[tt], 0.f);
                float ee = __expf(a);
                float m  = ee * (gxv[r][tt] + dlt[tt][r]);
                sA[tt] += ee;
                mxA[tt] = fmaxf(mxA[tt], m);
            }
        }
    }

    if (curD >= 0) {
        #pragma unroll
        for (int tt = 0; tt < 4; ++tt) {
            size_t off = (size_t)curD*CC + lm + 16*tt;
            atomicAdd(&esum[off], sA[tt]);
            atomicMax(&outb[off], fmono(mxA[tt]));
        }
    }
}

// ---- output kernel (MFMA, identity k-perm) -----------------------------------------------
__global__ __launch_bounds__(256, 2) void out_mfma_kernel(
    const unsigned* outb_in,            // aliases out -- no restrict
    const float* __restrict__ esum,
    const float* __restrict__ W_out, const float* __restrict__ b_out,
    float* out, int N)
{
    const int tid = threadIdx.x;
    const int lane = tid & 63;
    const int wid  = tid >> 6;
    const int lm = lane & 15;
    const int lg = lane >> 4;

    __shared__ __align__(16) unsigned short swt[64 * WPAD];
    for (int idx = tid; idx < 4096; idx += 256) {
        int o = idx >> 6, k = idx & 63;
        swt[o*WPAD + k] = f2b(W_out[(size_t)o*64 + k]);
    }
    __syncthreads();

    const int wbase = blockIdx.x * 64 + wid * 16;
    if (wbase >= N) return;

    const int row = min(wbase + lm, N-1);
    const unsigned* up = &outb_in[(size_t)row*CC];
    const float*    ep = &esum[(size_t)row*CC];
    s16x8 Alo, Ahi;
    #pragma unroll
    for (int half = 0; half < 2; ++half) {
        int kb = half*32 + lg*8;
        uint4  u0 = *(const uint4*)&up[kb];
        uint4  u1 = *(const uint4*)&up[kb+4];
        float4 e0 = *(const float4*)&ep[kb];
        float4 e1 = *(const float4*)&ep[kb+4];
        unsigned uu[8] = {u0.x,u0.y,u0.z,u0.w,u1.x,u1.y,u1.z,u1.w};
        float    ee[8] = {e0.x,e0.y,e0.z,e0.w,e1.x,e1.y,e1.z,e1.w};
        #pragma unroll
        for (int j = 0; j < 8; ++j) {
            unsigned u = uu[j];
            u = (u >> 31) ? (u ^ 0x80000000u) : ~u;    // inverse of fmono
            float v = __fdividef(__uint_as_float(u), ee[j]);
            if (half == 0) Alo[j] = (short)f2b(v); else Ahi[j] = (short)f2b(v);
        }
    }

    f32x4 zz[4];
    #pragma unroll
    for (int tt = 0; tt < 4; ++tt) {
        s16x8 b0 = *(const s16x8*)&swt[(lm + 16*tt)*WPAD + lg*8];
        s16x8 b1 = *(const s16x8*)&swt[(lm + 16*tt)*WPAD + 32 + lg*8];
        f32x4 z = {0.f, 0.f, 0.f, 0.f};
        z = __builtin_amdgcn_mfma_f32_16x16x32_bf16(Alo, b0, z, 0, 0, 0);
        zz[tt] = __builtin_amdgcn_mfma_f32_16x16x32_bf16(Ahi, b1, z, 0, 0, 0);
    }
    float bo[4];
    #pragma unroll
    for (int tt = 0; tt < 4; ++tt) bo[tt] = b_out[lm + 16*tt];

    #pragma unroll
    for (int r = 0; r < 4; ++r) {
        int n = wbase + lg*4 + r;
        if (n < N) {
            #pragma unroll
            for (int tt = 0; tt < 4; ++tt)
                out[(size_t)n*CC + lm + 16*tt] = fmaxf(zz[tt][r] + bo[tt], 0.f);
        }
    }
}

extern "C" void kernel_launch(void* const* d_in, const int* in_sizes, int n_in,
                              void* d_out, int out_size, void* d_ws, size_t ws_size,
                              hipStream_t stream)
{
    const float* x     = (const float*)d_in[0];
    const float* pos   = (const float*)d_in[1];
    const int*   ei    = (const int*)d_in[2];
    const float* W_in  = (const float*)d_in[3];
    const float* b_in  = (const float*)d_in[4];
    const float* W_out = (const float*)d_in[5];
    const float* b_out = (const float*)d_in[6];
    const float* W_lin = (const float*)d_in[7];
    const float* W_src = (const float*)d_in[8];
    const float* W_dst = (const float*)d_in[9];
    const float* pW1   = (const float*)d_in[10];
    const float* pb1   = (const float*)d_in[11];
    const float* pW2   = (const float*)d_in[12];
    const float* pb2   = (const float*)d_in[13];
    const float* aW1   = (const float*)d_in[14];
    const float* ab1   = (const float*)d_in[15];
    const float* aW2   = (const float*)d_in[16];
    const float* ab2   = (const float*)d_in[17];

    const int N = in_sizes[0] / CC;
    const int E = in_sizes[2] / 2;
    const size_t nc = (size_t)N * CC;

    char* wsb = (char*)d_ws;
    unsigned short* ASb = (unsigned short*)wsb;        // nc * 2B
    unsigned short* ADb = ASb + nc;                    // nc * 2B
    unsigned short* xvb = ADb + nc;                    // nc * 2B
    float* esum = (float*)(((size_t)(xvb + nc) + 15) & ~(size_t)15);   // nc * 4B
    unsigned* cnt       = (unsigned*)(esum + nc);
    unsigned* chunk_off = cnt + N;
    unsigned* cursor    = chunk_off + N;
    unsigned* partials  = cursor + N;                  // 1024 entries
    size_t rec_off = ((size_t)((char*)(partials + 1024) - wsb) + 15) & ~(size_t)15;
    int2* rec = (int2*)(wsb + rec_off);
    unsigned* outb = (unsigned*)d_out;

    hipMemsetAsync(esum, 0, nc*sizeof(float), stream);
    hipMemsetAsync(outb, 0, nc*sizeof(float), stream);
    hipMemsetAsync(cnt, 0, (size_t)N*sizeof(unsigned), stream);

    const int nblk = (N + 63) / 64;
    node_mfma_kernel<<<nblk, 256, 0, stream>>>(x, W_in, b_in, W_src, W_dst, W_lin, aW1,
                                               ASb, ADb, xvb, ei, cnt, N, E);
    const int nchunks = (N + 1023) / 1024;
    scan1_kernel<<<nchunks, SCAN_T, 0, stream>>>(cnt, chunk_off, partials, N);
    scan2_kernel<<<1, 1024, 0, stream>>>(partials, nchunks);
    scan3_kernel<<<(N + 255)/256, 256, 0, stream>>>(chunk_off, partials, cursor, N);
    scatter_kernel<<<2048, 256, 0, stream>>>(ei, cursor, rec, N, E);
    edge_mfma_kernel<<<2048, 256, 0, stream>>>(rec, pos, ADb, ASb, xvb,
                                               pW1, pb1, pW2, pb2, aW1, ab1, aW2, ab2,
                                               esum, outb, N, E);
    out_mfma_kernel<<<nblk, 256, 0, stream>>>(outb, esum, W_out, b_out, (float*)d_out, N);
}

// Round 20
// 409.889 us; speedup vs baseline: 1.2615x; 1.1452x over previous
//
#include <hip/hip_runtime.h>
#include <hip/hip_bf16.h>

#define CC 64
#define WPAD 72

typedef __attribute__((ext_vector_type(8))) short s16x8;
typedef __attribute__((ext_vector_type(4))) float f32x4;

__device__ __forceinline__ unsigned short f2b(float f) {   // f32 -> bf16 via HW cvt (RNE)
    __bf16 h = (__bf16)f;
    return __builtin_bit_cast(unsigned short, h);
}
__device__ __forceinline__ float b2f(unsigned short b) {   // bf16 bits -> f32
    return __uint_as_float((unsigned)b << 16);
}
__device__ __forceinline__ unsigned fmono(float f) {       // order-preserving f32->u32
    unsigned u = __float_as_uint(f);
    return u ^ ((unsigned)((int)u >> 31) | 0x80000000u);
}

// ---- node kernel (MFMA) + fused dst-histogram (identity k-perm, WPAD=72) -----------------
__global__ __launch_bounds__(256, 2) void node_mfma_kernel(
    const float* __restrict__ x,
    const float* __restrict__ W_in, const float* __restrict__ b_in,
    const float* __restrict__ W_src, const float* __restrict__ W_dst,
    const float* __restrict__ W_lin, const float* __restrict__ aW1,
    unsigned short* __restrict__ ASb, unsigned short* __restrict__ ADb,
    unsigned short* __restrict__ xvb,
    const int* __restrict__ ei, unsigned* __restrict__ cnt, int N, int E)
{
    const int tid = threadIdx.x;
    const int lane = tid & 63;
    const int wid  = tid >> 6;
    const int lm = lane & 15;
    const int lg = lane >> 4;

    __shared__ __align__(16) unsigned short swt[5][64 * WPAD];
    __shared__ __align__(16) unsigned short tb[4][16 * WPAD];

    {
        const float* Wr[4] = {W_in, W_src, W_dst, W_lin};
        #pragma unroll
        for (int w = 0; w < 4; ++w)
            for (int idx = tid; idx < 4096; idx += 256) {
                int o = idx >> 6, k = idx & 63;
                swt[w][o*WPAD + k] = f2b(Wr[w][(size_t)o*64 + k]);
            }
        for (int idx = tid; idx < 4096; idx += 256) {
            int k = idx >> 6, o = idx & 63;
            swt[4][o*WPAD + k] = f2b(aW1[idx]);     // aW1[k][o]
        }
    }
    __syncthreads();

    const int wbase = blockIdx.x * 64 + wid * 16;
    unsigned short* tbw = tb[wid];

    if (wbase < N) {
        float bin[4];
        #pragma unroll
        for (int tt = 0; tt < 4; ++tt) bin[tt] = b_in[lm + 16*tt];

        const int xrow = min(wbase + lm, N-1);
        const float* xp = &x[(size_t)xrow*CC];
        float4 a0 = *(const float4*)&xp[lg*8];
        float4 a1 = *(const float4*)&xp[lg*8 + 4];
        float4 a2 = *(const float4*)&xp[32 + lg*8];
        float4 a3 = *(const float4*)&xp[32 + lg*8 + 4];
        s16x8 Xlo, Xhi;
        Xlo[0]=(short)f2b(a0.x); Xlo[1]=(short)f2b(a0.y); Xlo[2]=(short)f2b(a0.z); Xlo[3]=(short)f2b(a0.w);
        Xlo[4]=(short)f2b(a1.x); Xlo[5]=(short)f2b(a1.y); Xlo[6]=(short)f2b(a1.z); Xlo[7]=(short)f2b(a1.w);
        Xhi[0]=(short)f2b(a2.x); Xhi[1]=(short)f2b(a2.y); Xhi[2]=(short)f2b(a2.z); Xhi[3]=(short)f2b(a2.w);
        Xhi[4]=(short)f2b(a3.x); Xhi[5]=(short)f2b(a3.y); Xhi[6]=(short)f2b(a3.z); Xhi[7]=(short)f2b(a3.w);

        auto mm = [&](s16x8 alo, s16x8 ahi, int w, f32x4* zz) {
            #pragma unroll
            for (int tt = 0; tt < 4; ++tt) {
                s16x8 b0 = *(const s16x8*)&swt[w][(lm + 16*tt)*WPAD + lg*8];
                s16x8 b1 = *(const s16x8*)&swt[w][(lm + 16*tt)*WPAD + 32 + lg*8];
                f32x4 z = {0.f, 0.f, 0.f, 0.f};
                z = __builtin_amdgcn_mfma_f32_16x16x32_bf16(alo, b0, z, 0, 0, 0);
                zz[tt] = __builtin_amdgcn_mfma_f32_16x16x32_bf16(ahi, b1, z, 0, 0, 0);
            }
        };
        auto transpose = [&](const f32x4* zz, s16x8& olo, s16x8& ohi) {
            #pragma unroll
            for (int tt = 0; tt < 4; ++tt)
                #pragma unroll
                for (int r = 0; r < 4; ++r)
                    tbw[(lg*4+r)*WPAD + lm + 16*tt] = f2b(zz[tt][r]);
            __builtin_amdgcn_wave_barrier();
            olo = *(const s16x8*)&tbw[lm*WPAD + lg*8];
            ohi = *(const s16x8*)&tbw[lm*WPAD + 32 + lg*8];
            __builtin_amdgcn_wave_barrier();
        };
        auto store_perm = [&](const f32x4* zz, unsigned short* out) {
            #pragma unroll
            for (int r = 0; r < 4; ++r) {
                int n = wbase + lg*4 + r;
                if (n < N) {
                    ushort4 v = make_ushort4(f2b(zz[0][r]), f2b(zz[1][r]),
                                             f2b(zz[2][r]), f2b(zz[3][r]));
                    *(ushort4*)&out[(size_t)n*CC + lm*4] = v;
                }
            }
        };

        f32x4 zh[4], zt[4], zo[4];
        mm(Xlo, Xhi, 0, zh);
        #pragma unroll
        for (int tt = 0; tt < 4; ++tt)
            #pragma unroll
            for (int r = 0; r < 4; ++r)
                zh[tt][r] = fmaxf(zh[tt][r] + bin[tt], 0.f);
        s16x8 Hlo, Hhi;
        transpose(zh, Hlo, Hhi);

        mm(Hlo, Hhi, 1, zt);
        { s16x8 Tlo, Thi; transpose(zt, Tlo, Thi); mm(Tlo, Thi, 4, zo); }
        store_perm(zo, ASb);

        mm(Hlo, Hhi, 2, zt);
        { s16x8 Tlo, Thi; transpose(zt, Tlo, Thi); mm(Tlo, Thi, 4, zo); }
        store_perm(zo, ADb);

        mm(Hlo, Hhi, 3, zo);
        store_perm(zo, xvb);
    }

    const int total = E + N;
    for (int e = blockIdx.x*256 + tid; e < total; e += gridDim.x*256) {
        int d = (e < E) ? min(max(ei[(size_t)E + e], 0), N-1) : (e - E);
        atomicAdd(&cnt[d], 1u);
    }
}

// ---- exclusive scan (3 kernels) + scatter ------------------------------------------------
#define SCAN_T 256
__global__ __launch_bounds__(SCAN_T) void scan1_kernel(
    const unsigned* __restrict__ cnt, unsigned* __restrict__ chunk_off,
    unsigned* __restrict__ partials, int n)
{
    __shared__ unsigned sh[SCAN_T];
    const int t = threadIdx.x, b0 = blockIdx.x * (SCAN_T*4);
    unsigned v[4], s = 0;
    #pragma unroll
    for (int i = 0; i < 4; ++i) {
        int idx = b0 + t*4 + i;
        v[i] = (idx < n) ? cnt[idx] : 0u;
        s += v[i];
    }
    sh[t] = s; __syncthreads();
    for (int d = 1; d < SCAN_T; d <<= 1) {
        unsigned xv = (t >= d) ? sh[t-d] : 0u;
        __syncthreads();
        sh[t] += xv;
        __syncthreads();
    }
    unsigned run = (t > 0) ? sh[t-1] : 0u;
    #pragma unroll
    for (int i = 0; i < 4; ++i) {
        int idx = b0 + t*4 + i;
        if (idx < n) chunk_off[idx] = run;
        run += v[i];
    }
    if (t == SCAN_T-1) partials[blockIdx.x] = sh[SCAN_T-1];
}

__global__ __launch_bounds__(1024) void scan2_kernel(unsigned* __restrict__ partials, int nb)
{
    __shared__ unsigned sh[1024];
    const int t = threadIdx.x;
    sh[t] = (t < nb) ? partials[t] : 0u; __syncthreads();
    for (int d = 1; d < 1024; d <<= 1) {
        unsigned xv = (t >= d) ? sh[t-d] : 0u;
        __syncthreads();
        sh[t] += xv;
        __syncthreads();
    }
    if (t < nb) partials[t] = (t > 0) ? sh[t-1] : 0u;
}

__global__ __launch_bounds__(256) void scan3_kernel(
    const unsigned* __restrict__ chunk_off, const unsigned* __restrict__ partials,
    unsigned* __restrict__ cursor, int n)
{
    int i = blockIdx.x*256 + threadIdx.x;
    if (i < n) cursor[i] = chunk_off[i] + partials[i >> 10];
}

__global__ __launch_bounds__(256) void scatter_kernel(
    const int* __restrict__ ei, unsigned* __restrict__ cursor,
    int2* __restrict__ rec, int N, int E)
{
    const int total = E + N;
    for (int e = blockIdx.x*256 + threadIdx.x; e < total; e += gridDim.x*256) {
        int s, d;
        if (e < E) {
            s = min(max(ei[e], 0), N-1);
            d = min(max(ei[(size_t)E + e], 0), N-1);
        } else { s = d = e - E; }
        unsigned p = atomicAdd(&cursor[d], 1u);
        rec[p] = make_int2(s, d);
    }
}

// ---- edge kernel: permuted-k, hoisted pW1 registers, interior-run plain stores -----------
__global__ __launch_bounds__(256, 3) void edge_mfma_kernel(
    const int2* __restrict__ rec, const float* __restrict__ pos,
    const unsigned short* __restrict__ ADb, const unsigned short* __restrict__ ASb,
    const unsigned short* __restrict__ xvb,
    const float* __restrict__ pW1, const float* __restrict__ pb1,
    const float* __restrict__ pW2, const float* __restrict__ pb2,
    const float* __restrict__ aW1, const float* __restrict__ ab1,
    const float* __restrict__ aW2, const float* __restrict__ ab2,
    float* __restrict__ esum, unsigned* __restrict__ outb,
    int N, int E)
{
    const int tid = threadIdx.x;
    const int lane = tid & 63;
    const int wid  = tid >> 6;
    const int lm = lane & 15;
    const int lg = lane >> 4;

    __shared__ __align__(16) unsigned short swt[3][64 * WPAD];
    __shared__ __align__(16) unsigned short tb[4][16 * WPAD];

    {
        const float* Wsrc[3] = {pW2, aW1, aW2};
        #pragma unroll
        for (int w = 0; w < 3; ++w)
            for (int idx = tid; idx < 4096; idx += 256) {
                int p = idx >> 6, o = idx & 63;
                int c = (p >> 2) + 16*(p & 3);
                swt[w][o*WPAD + p] = f2b(Wsrc[w][(size_t)c*64 + o]);
            }
    }
    __syncthreads();

    // hoisted loop-invariant pW1/pb1 weights, per-lane (bf16-quantized to match prior math)
    float w0v[16], w1v[16], w2v[16], wbv[16];
    #pragma unroll
    for (int j = 0; j < 16; ++j) {
        int p = lg*8 + (j & 7) + 32*(j >> 3);
        int k = (p >> 2) + 16*(p & 3);
        w0v[j] = b2f(f2b(pW1[k]));
        w1v[j] = b2f(f2b(pW1[64 + k]));
        w2v[j] = b2f(f2b(pW1[128 + k]));
        wbv[j] = b2f(f2b(pb1[k]));
    }

    float pb2v[4], ab1v[4], ab2v[4];
    #pragma unroll
    for (int tt = 0; tt < 4; ++tt) {
        pb2v[tt] = pb2[lm + 16*tt];
        ab1v[tt] = ab1[lm + 16*tt];
        ab2v[tt] = ab2[lm + 16*tt];
    }

    unsigned short* tbw = tb[wid];
    const int total = E + N;
    const int ntiles = (total + 15) >> 4;
    const int nwaves = gridDim.x * 4;
    const int tpw = (ntiles + nwaves - 1) / nwaves;
    const int gw = blockIdx.x * 4 + wid;
    const int t0 = min(gw * tpw, ntiles);
    const int t1 = min(t0 + tpw, ntiles);
    if (t0 >= t1) return;
    const int nstep = t1 - t0;
    const int qlen  = 4 * nstep;
    const int rbase = t0 << 4;
    const int pq = rbase + (lm >> 2)*qlen + (lm & 3);
    const int gq = rbase + lg*qlen;

    int   curD = -1;
    bool  firstF = true;
    float sA[4]  = {0.f, 0.f, 0.f, 0.f};
    float mxA[4] = {-INFINITY, -INFINITY, -INFINITY, -INFINITY};

    int2 rp_n, rg_n0, rg_n1, rg_n2, rg_n3;
    rp_n  = rec[min(pq, total-1)];
    rg_n0 = rec[min(gq+0, total-1)];
    rg_n1 = rec[min(gq+1, total-1)];
    rg_n2 = rec[min(gq+2, total-1)];
    rg_n3 = rec[min(gq+3, total-1)];

    for (int step = 0; step < nstep; ++step) {
        const int2 rp = rp_n;
        int sg[4], dg[4];
        sg[0] = rg_n0.x; dg[0] = rg_n0.y;
        sg[1] = rg_n1.x; dg[1] = rg_n1.y;
        sg[2] = rg_n2.x; dg[2] = rg_n2.y;
        sg[3] = rg_n3.x; dg[3] = rg_n3.y;
        int actm = 0;
        #pragma unroll
        for (int r = 0; r < 4; ++r)
            if (gq + step*4 + r < total) actm |= (1 << r);

        float q0 = pos[(size_t)rp.y*3+0] - pos[(size_t)rp.x*3+0];
        float q1 = pos[(size_t)rp.y*3+1] - pos[(size_t)rp.x*3+1];
        float q2 = pos[(size_t)rp.y*3+2] - pos[(size_t)rp.x*3+2];

        float gd[4][4], gxv[4][4];
        #pragma unroll
        for (int r = 0; r < 4; ++r) {
            const ushort4 a4 = *(const ushort4*)&ADb[(size_t)dg[r]*CC + lm*4];
            const ushort4 s4 = *(const ushort4*)&ASb[(size_t)sg[r]*CC + lm*4];
            const ushort4 x4 = *(const ushort4*)&xvb[(size_t)sg[r]*CC + lm*4];
            gd[r][0] = b2f(a4.x) - b2f(s4.x);
            gd[r][1] = b2f(a4.y) - b2f(s4.y);
            gd[r][2] = b2f(a4.z) - b2f(s4.z);
            gd[r][3] = b2f(a4.w) - b2f(s4.w);
            gxv[r][0] = b2f(x4.x); gxv[r][1] = b2f(x4.y);
            gxv[r][2] = b2f(x4.z); gxv[r][3] = b2f(x4.w);
        }

        if (step + 1 < nstep) {
            const int pn = pq + (step+1)*4;
            const int gn = gq + (step+1)*4;
            rp_n  = rec[min(pn,   total-1)];
            rg_n0 = rec[min(gn+0, total-1)];
            rg_n1 = rec[min(gn+1, total-1)];
            rg_n2 = rec[min(gn+2, total-1)];
            rg_n3 = rec[min(gn+3, total-1)];
        }

        // ---- p1 = relu(pdiff@pW1 + pb1) in A-frag layout (registers only) ----
        s16x8 Alo, Ahi;
        #pragma unroll
        for (int j = 0; j < 16; ++j) {
            float v = fmaxf(fmaf(q0, w0v[j], fmaf(q1, w1v[j], fmaf(q2, w2v[j], wbv[j]))), 0.f);
            short b = (short)f2b(v);
            if (j < 8) Alo[j] = b; else Ahi[j-8] = b;
        }

        // ---- layer 1: delta = relu(p1 @ pW2 + pb2) ----
        f32x4 dlt[4];
        #pragma unroll
        for (int tt = 0; tt < 4; ++tt) {
            s16x8 b0 = *(const s16x8*)&swt[0][(lm + 16*tt)*WPAD + lg*8];
            s16x8 b1 = *(const s16x8*)&swt[0][(lm + 16*tt)*WPAD + 32 + lg*8];
            f32x4 z = {0.f, 0.f, 0.f, 0.f};
            z = __builtin_amdgcn_mfma_f32_16x16x32_bf16(Alo, b0, z, 0, 0, 0);
            z = __builtin_amdgcn_mfma_f32_16x16x32_bf16(Ahi, b1, z, 0, 0, 0);
            #pragma unroll
            for (int r = 0; r < 4; ++r) dlt[tt][r] = fmaxf(z[r] + pb2v[tt], 0.f);
        }

        // ---- transpose 1: packed b64 writes (position 4*lm+tt == channel lm+16tt) ----
        #pragma unroll
        for (int r = 0; r < 4; ++r) {
            ushort4 v = make_ushort4(f2b(dlt[0][r]), f2b(dlt[1][r]),
                                     f2b(dlt[2][r]), f2b(dlt[3][r]));
            *(ushort4*)&tbw[(lg*4+r)*WPAD + 4*lm] = v;
        }
        __builtin_amdgcn_wave_barrier();
        s16x8 Dlo = *(const s16x8*)&tbw[lm*WPAD + lg*8];
        s16x8 Dhi = *(const s16x8*)&tbw[lm*WPAD + 32 + lg*8];
        __builtin_amdgcn_wave_barrier();

        // ---- layer 2: h1 = relu(gd + delta@aW1 + ab1) -> packed transpose 2 ----
        float h1v[4][4];
        #pragma unroll
        for (int tt = 0; tt < 4; ++tt) {
            s16x8 b0 = *(const s16x8*)&swt[1][(lm + 16*tt)*WPAD + lg*8];
            s16x8 b1 = *(const s16x8*)&swt[1][(lm + 16*tt)*WPAD + 32 + lg*8];
            f32x4 z = {0.f, 0.f, 0.f, 0.f};
            z = __builtin_amdgcn_mfma_f32_16x16x32_bf16(Dlo, b0, z, 0, 0, 0);
            z = __builtin_amdgcn_mfma_f32_16x16x32_bf16(Dhi, b1, z, 0, 0, 0);
            #pragma unroll
            for (int r = 0; r < 4; ++r)
                h1v[tt][r] = fmaxf(z[r] + gd[r][tt] + ab1v[tt], 0.f);
        }
        #pragma unroll
        for (int r = 0; r < 4; ++r) {
            ushort4 v = make_ushort4(f2b(h1v[0][r]), f2b(h1v[1][r]),
                                     f2b(h1v[2][r]), f2b(h1v[3][r]));
            *(ushort4*)&tbw[(lg*4+r)*WPAD + 4*lm] = v;
        }
        __builtin_amdgcn_wave_barrier();
        s16x8 Hlo = *(const s16x8*)&tbw[lm*WPAD + lg*8];
        s16x8 Hhi = *(const s16x8*)&tbw[lm*WPAD + 32 + lg*8];
        __builtin_amdgcn_wave_barrier();

        // ---- layer 3 + run-carried aggregation ----
        f32x4 zz[4];
        #pragma unroll
        for (int tt = 0; tt < 4; ++tt) {
            s16x8 b0 = *(const s16x8*)&swt[2][(lm + 16*tt)*WPAD + lg*8];
            s16x8 b1 = *(const s16x8*)&swt[2][(lm + 16*tt)*WPAD + 32 + lg*8];
            f32x4 z = {0.f, 0.f, 0.f, 0.f};
            z = __builtin_amdgcn_mfma_f32_16x16x32_bf16(Hlo, b0, z, 0, 0, 0);
            zz[tt] = __builtin_amdgcn_mfma_f32_16x16x32_bf16(Hhi, b1, z, 0, 0, 0);
        }

        #pragma unroll
        for (int r = 0; r < 4; ++r) {
            if (!(actm & (1 << r))) continue;
            if (dg[r] != curD) {
                if (curD >= 0) {
                    if (firstF) {
                        #pragma unroll
                        for (int tt = 0; tt < 4; ++tt) {
                            size_t off = (size_t)curD*CC + lm + 16*tt;
                            atomicAdd(&esum[off], sA[tt]);
                            atomicMax(&outb[off], fmono(mxA[tt]));
                        }
                    } else {
                        #pragma unroll
                        for (int tt = 0; tt < 4; ++tt) {
                            size_t off = (size_t)curD*CC + lm + 16*tt;
                            esum[off] = sA[tt];
                            outb[off] = fmono(mxA[tt]);
                        }
                    }
                    firstF = false;
                }
                curD = dg[r];
                #pragma unroll
                for (int tt = 0; tt < 4; ++tt) { sA[tt] = 0.f; mxA[tt] = -INFINITY; }
            }
            #pragma unroll
            for (int tt = 0; tt < 4; ++tt) {
                float a  = fmaxf(zz[tt][r] + ab2v[tt], 0.f);
                float ee = __expf(a);
                float m  = ee * (gxv[r][tt] + dlt[tt][r]);
                sA[tt] += ee;
                mxA[tt] = fmaxf(mxA[tt], m);
            }
        }
    }

    if (curD >= 0) {
        #pragma unroll
        for (int tt = 0; tt < 4; ++tt) {
            size_t off = (size_t)curD*CC + lm + 16*tt;
            atomicAdd(&esum[off], sA[tt]);
            atomicMax(&outb[off], fmono(mxA[tt]));
        }
    }
}

// ---- output kernel (MFMA, identity k-perm) -----------------------------------------------
__global__ __launch_bounds__(256, 2) void out_mfma_kernel(
    const unsigned* outb_in,            // aliases out -- no restrict
    const float* __restrict__ esum,
    const float* __restrict__ W_out, const float* __restrict__ b_out,
    float* out, int N)
{
    const int tid = threadIdx.x;
    const int lane = tid & 63;
    const int wid  = tid >> 6;
    const int lm = lane & 15;
    const int lg = lane >> 4;

    __shared__ __align__(16) unsigned short swt[64 * WPAD];
    for (int idx = tid; idx < 4096; idx += 256) {
        int o = idx >> 6, k = idx & 63;
        swt[o*WPAD + k] = f2b(W_out[(size_t)o*64 + k]);
    }
    __syncthreads();

    const int wbase = blockIdx.x * 64 + wid * 16;
    if (wbase >= N) return;

    const int row = min(wbase + lm, N-1);
    const unsigned* up = &outb_in[(size_t)row*CC];
    const float*    ep = &esum[(size_t)row*CC];
    s16x8 Alo, Ahi;
    #pragma unroll
    for (int half = 0; half < 2; ++half) {
        int kb = half*32 + lg*8;
        uint4  u0 = *(const uint4*)&up[kb];
        uint4  u1 = *(const uint4*)&up[kb+4];
        float4 e0 = *(const float4*)&ep[kb];
        float4 e1 = *(const float4*)&ep[kb+4];
        unsigned uu[8] = {u0.x,u0.y,u0.z,u0.w,u1.x,u1.y,u1.z,u1.w};
        float    ee[8] = {e0.x,e0.y,e0.z,e0.w,e1.x,e1.y,e1.z,e1.w};
        #pragma unroll
        for (int j = 0; j < 8; ++j) {
            unsigned u = uu[j];
            u = (u >> 31) ? (u ^ 0x80000000u) : ~u;    // inverse of fmono
            float v = __fdividef(__uint_as_float(u), ee[j]);
            if (half == 0) Alo[j] = (short)f2b(v); else Ahi[j] = (short)f2b(v);
        }
    }

    f32x4 zz[4];
    #pragma unroll
    for (int tt = 0; tt < 4; ++tt) {
        s16x8 b0 = *(const s16x8*)&swt[(lm + 16*tt)*WPAD + lg*8];
        s16x8 b1 = *(const s16x8*)&swt[(lm + 16*tt)*WPAD + 32 + lg*8];
        f32x4 z = {0.f, 0.f, 0.f, 0.f};
        z = __builtin_amdgcn_mfma_f32_16x16x32_bf16(Alo, b0, z, 0, 0, 0);
        zz[tt] = __builtin_amdgcn_mfma_f32_16x16x32_bf16(Ahi, b1, z, 0, 0, 0);
    }
    float bo[4];
    #pragma unroll
    for (int tt = 0; tt < 4; ++tt) bo[tt] = b_out[lm + 16*tt];

    #pragma unroll
    for (int r = 0; r < 4; ++r) {
        int n = wbase + lg*4 + r;
        if (n < N) {
            #pragma unroll
            for (int tt = 0; tt < 4; ++tt)
                out[(size_t)n*CC + lm + 16*tt] = fmaxf(zz[tt][r] + bo[tt], 0.f);
        }
    }
}

extern "C" void kernel_launch(void* const* d_in, const int* in_sizes, int n_in,
                              void* d_out, int out_size, void* d_ws, size_t ws_size,
                              hipStream_t stream)
{
    const float* x     = (const float*)d_in[0];
    const float* pos   = (const float*)d_in[1];
    const int*   ei    = (const int*)d_in[2];
    const float* W_in  = (const float*)d_in[3];
    const float* b_in  = (const float*)d_in[4];
    const float* W_out = (const float*)d_in[5];
    const float* b_out = (const float*)d_in[6];
    const float* W_lin = (const float*)d_in[7];
    const float* W_src = (const float*)d_in[8];
    const float* W_dst = (const float*)d_in[9];
    const float* pW1   = (const float*)d_in[10];
    const float* pb1   = (const float*)d_in[11];
    const float* pW2   = (const float*)d_in[12];
    const float* pb2   = (const float*)d_in[13];
    const float* aW1   = (const float*)d_in[14];
    const float* ab1   = (const float*)d_in[15];
    const float* aW2   = (const float*)d_in[16];
    const float* ab2   = (const float*)d_in[17];

    const int N = in_sizes[0] / CC;
    const int E = in_sizes[2] / 2;
    const size_t nc = (size_t)N * CC;

    char* wsb = (char*)d_ws;
    unsigned short* ASb = (unsigned short*)wsb;        // nc * 2B
    unsigned short* ADb = ASb + nc;                    // nc * 2B
    unsigned short* xvb = ADb + nc;                    // nc * 2B
    float* esum = (float*)(((size_t)(xvb + nc) + 15) & ~(size_t)15);   // nc * 4B
    unsigned* cnt       = (unsigned*)(esum + nc);
    unsigned* chunk_off = cnt + N;
    unsigned* cursor    = chunk_off + N;
    unsigned* partials  = cursor + N;                  // 1024 entries
    size_t rec_off = ((size_t)((char*)(partials + 1024) - wsb) + 15) & ~(size_t)15;
    int2* rec = (int2*)(wsb + rec_off);
    unsigned* outb = (unsigned*)d_out;

    // esum and cnt are contiguous -> one memset covers both
    hipMemsetAsync(esum, 0, (nc + (size_t)N)*sizeof(float), stream);
    hipMemsetAsync(outb, 0, nc*sizeof(float), stream);

    const int nblk = (N + 63) / 64;
    node_mfma_kernel<<<nblk, 256, 0, stream>>>(x, W_in, b_in, W_src, W_dst, W_lin, aW1,
                                               ASb, ADb, xvb, ei, cnt, N, E);
    const int nchunks = (N + 1023) / 1024;
    scan1_kernel<<<nchunks, SCAN_T, 0, stream>>>(cnt, chunk_off, partials, N);
    scan2_kernel<<<1, 1024, 0, stream>>>(partials, nchunks);
    scan3_kernel<<<(N + 255)/256, 256, 0, stream>>>(chunk_off, partials, cursor, N);
    scatter_kernel<<<2048, 256, 0, stream>>>(ei, cursor, rec, N, E);
    edge_mfma_kernel<<<2048, 256, 0, stream>>>(rec, pos, ADb, ASb, xvb,
                                               pW1, pb1, pW2, pb2, aW1, ab1, aW2, ab2,
                                               esum, outb, N, E);
    out_mfma_kernel<<<nblk, 256, 0, stream>>>(outb, esum, W_out, b_out, (float*)d_out, N);
}

// Round 21
// 408.190 us; speedup vs baseline: 1.2668x; 1.0042x over previous
//
#include <hip/hip_runtime.h>
#include <hip/hip_bf16.h>

#define CC 64
#define WPAD 72

typedef __attribute__((ext_vector_type(8))) short s16x8;
typedef __attribute__((ext_vector_type(4))) float f32x4;

__device__ __forceinline__ unsigned short f2b(float f) {   // f32 -> bf16 via HW cvt (RNE)
    __bf16 h = (__bf16)f;
    return __builtin_bit_cast(unsigned short, h);
}
__device__ __forceinline__ float b2f(unsigned short b) {   // bf16 bits -> f32
    return __uint_as_float((unsigned)b << 16);
}
__device__ __forceinline__ unsigned fmono(float f) {       // order-preserving f32->u32
    unsigned u = __float_as_uint(f);
    return u ^ ((unsigned)((int)u >> 31) | 0x80000000u);
}

// ---- node kernel (MFMA), 256 nodes/block (4 groups/wave) + fused dst-histogram -----------
__global__ __launch_bounds__(256, 2) void node_mfma_kernel(
    const float* __restrict__ x,
    const float* __restrict__ W_in, const float* __restrict__ b_in,
    const float* __restrict__ W_src, const float* __restrict__ W_dst,
    const float* __restrict__ W_lin, const float* __restrict__ aW1,
    unsigned short* __restrict__ ASb, unsigned short* __restrict__ ADb,
    unsigned short* __restrict__ xvb,
    const int* __restrict__ ei, unsigned* __restrict__ cnt, int N, int E)
{
    const int tid = threadIdx.x;
    const int lane = tid & 63;
    const int wid  = tid >> 6;
    const int lm = lane & 15;
    const int lg = lane >> 4;

    __shared__ __align__(16) unsigned short swt[5][64 * WPAD];
    __shared__ __align__(16) unsigned short tb[4][16 * WPAD];

    {
        const float* Wr[4] = {W_in, W_src, W_dst, W_lin};
        #pragma unroll
        for (int w = 0; w < 4; ++w)
            for (int idx = tid; idx < 4096; idx += 256) {
                int o = idx >> 6, k = idx & 63;
                swt[w][o*WPAD + k] = f2b(Wr[w][(size_t)o*64 + k]);
            }
        for (int idx = tid; idx < 4096; idx += 256) {
            int k = idx >> 6, o = idx & 63;
            swt[4][o*WPAD + k] = f2b(aW1[idx]);     // aW1[k][o]
        }
    }
    __syncthreads();

    unsigned short* tbw = tb[wid];
    float bin[4];
    #pragma unroll
    for (int tt = 0; tt < 4; ++tt) bin[tt] = b_in[lm + 16*tt];

    auto mm = [&](s16x8 alo, s16x8 ahi, int w, f32x4* zz) {
        #pragma unroll
        for (int tt = 0; tt < 4; ++tt) {
            s16x8 b0 = *(const s16x8*)&swt[w][(lm + 16*tt)*WPAD + lg*8];
            s16x8 b1 = *(const s16x8*)&swt[w][(lm + 16*tt)*WPAD + 32 + lg*8];
            f32x4 z = {0.f, 0.f, 0.f, 0.f};
            z = __builtin_amdgcn_mfma_f32_16x16x32_bf16(alo, b0, z, 0, 0, 0);
            zz[tt] = __builtin_amdgcn_mfma_f32_16x16x32_bf16(ahi, b1, z, 0, 0, 0);
        }
    };
    auto transpose = [&](const f32x4* zz, s16x8& olo, s16x8& ohi) {
        #pragma unroll
        for (int tt = 0; tt < 4; ++tt)
            #pragma unroll
            for (int r = 0; r < 4; ++r)
                tbw[(lg*4+r)*WPAD + lm + 16*tt] = f2b(zz[tt][r]);
        __builtin_amdgcn_wave_barrier();
        olo = *(const s16x8*)&tbw[lm*WPAD + lg*8];
        ohi = *(const s16x8*)&tbw[lm*WPAD + 32 + lg*8];
        __builtin_amdgcn_wave_barrier();
    };

    #pragma unroll 1
    for (int g = 0; g < 4; ++g) {
        const int wbase = blockIdx.x * 256 + g * 64 + wid * 16;
        if (wbase >= N) break;

        const int xrow = min(wbase + lm, N-1);
        const float* xp = &x[(size_t)xrow*CC];
        float4 a0 = *(const float4*)&xp[lg*8];
        float4 a1 = *(const float4*)&xp[lg*8 + 4];
        float4 a2 = *(const float4*)&xp[32 + lg*8];
        float4 a3 = *(const float4*)&xp[32 + lg*8 + 4];
        s16x8 Xlo, Xhi;
        Xlo[0]=(short)f2b(a0.x); Xlo[1]=(short)f2b(a0.y); Xlo[2]=(short)f2b(a0.z); Xlo[3]=(short)f2b(a0.w);
        Xlo[4]=(short)f2b(a1.x); Xlo[5]=(short)f2b(a1.y); Xlo[6]=(short)f2b(a1.z); Xlo[7]=(short)f2b(a1.w);
        Xhi[0]=(short)f2b(a2.x); Xhi[1]=(short)f2b(a2.y); Xhi[2]=(short)f2b(a2.z); Xhi[3]=(short)f2b(a2.w);
        Xhi[4]=(short)f2b(a3.x); Xhi[5]=(short)f2b(a3.y); Xhi[6]=(short)f2b(a3.z); Xhi[7]=(short)f2b(a3.w);

        auto store_perm = [&](const f32x4* zz, unsigned short* out) {
            #pragma unroll
            for (int r = 0; r < 4; ++r) {
                int n = wbase + lg*4 + r;
                if (n < N) {
                    ushort4 v = make_ushort4(f2b(zz[0][r]), f2b(zz[1][r]),
                                             f2b(zz[2][r]), f2b(zz[3][r]));
                    *(ushort4*)&out[(size_t)n*CC + lm*4] = v;
                }
            }
        };

        f32x4 zh[4], zt[4], zo[4];
        mm(Xlo, Xhi, 0, zh);
        #pragma unroll
        for (int tt = 0; tt < 4; ++tt)
            #pragma unroll
            for (int r = 0; r < 4; ++r)
                zh[tt][r] = fmaxf(zh[tt][r] + bin[tt], 0.f);
        s16x8 Hlo, Hhi;
        transpose(zh, Hlo, Hhi);

        mm(Hlo, Hhi, 1, zt);
        { s16x8 Tlo, Thi; transpose(zt, Tlo, Thi); mm(Tlo, Thi, 4, zo); }
        store_perm(zo, ASb);

        mm(Hlo, Hhi, 2, zt);
        { s16x8 Tlo, Thi; transpose(zt, Tlo, Thi); mm(Tlo, Thi, 4, zo); }
        store_perm(zo, ADb);

        mm(Hlo, Hhi, 3, zo);
        store_perm(zo, xvb);
    }

    const int total = E + N;
    for (int e = blockIdx.x*256 + tid; e < total; e += gridDim.x*256) {
        int d = (e < E) ? min(max(ei[(size_t)E + e], 0), N-1) : (e - E);
        atomicAdd(&cnt[d], 1u);
    }
}

// ---- exclusive scan (3 kernels) + scatter ------------------------------------------------
#define SCAN_T 256
__global__ __launch_bounds__(SCAN_T) void scan1_kernel(
    const unsigned* __restrict__ cnt, unsigned* __restrict__ chunk_off,
    unsigned* __restrict__ partials, int n)
{
    __shared__ unsigned sh[SCAN_T];
    const int t = threadIdx.x, b0 = blockIdx.x * (SCAN_T*4);
    unsigned v[4], s = 0;
    #pragma unroll
    for (int i = 0; i < 4; ++i) {
        int idx = b0 + t*4 + i;
        v[i] = (idx < n) ? cnt[idx] : 0u;
        s += v[i];
    }
    sh[t] = s; __syncthreads();
    for (int d = 1; d < SCAN_T; d <<= 1) {
        unsigned xv = (t >= d) ? sh[t-d] : 0u;
        __syncthreads();
        sh[t] += xv;
        __syncthreads();
    }
    unsigned run = (t > 0) ? sh[t-1] : 0u;
    #pragma unroll
    for (int i = 0; i < 4; ++i) {
        int idx = b0 + t*4 + i;
        if (idx < n) chunk_off[idx] = run;
        run += v[i];
    }
    if (t == SCAN_T-1) partials[blockIdx.x] = sh[SCAN_T-1];
}

__global__ __launch_bounds__(1024) void scan2_kernel(unsigned* __restrict__ partials, int nb)
{
    __shared__ unsigned sh[1024];
    const int t = threadIdx.x;
    sh[t] = (t < nb) ? partials[t] : 0u; __syncthreads();
    for (int d = 1; d < 1024; d <<= 1) {
        unsigned xv = (t >= d) ? sh[t-d] : 0u;
        __syncthreads();
        sh[t] += xv;
        __syncthreads();
    }
    if (t < nb) partials[t] = (t > 0) ? sh[t-1] : 0u;
}

__global__ __launch_bounds__(256) void scan3_kernel(
    const unsigned* __restrict__ chunk_off, const unsigned* __restrict__ partials,
    unsigned* __restrict__ cursor, int n)
{
    int i = blockIdx.x*256 + threadIdx.x;
    if (i < n) cursor[i] = chunk_off[i] + partials[i >> 10];
}

__global__ __launch_bounds__(256) void scatter_kernel(
    const int* __restrict__ ei, unsigned* __restrict__ cursor,
    int2* __restrict__ rec, int N, int E)
{
    const int total = E + N;
    for (int e = blockIdx.x*256 + threadIdx.x; e < total; e += gridDim.x*256) {
        int s, d;
        if (e < E) {
            s = min(max(ei[e], 0), N-1);
            d = min(max(ei[(size_t)E + e], 0), N-1);
        } else { s = d = e - E; }
        unsigned p = atomicAdd(&cursor[d], 1u);
        rec[p] = make_int2(s, d);
    }
}

// ---- edge kernel: permuted-k, hoisted pW1 registers, interior-run plain stores -----------
__global__ __launch_bounds__(256, 3) void edge_mfma_kernel(
    const int2* __restrict__ rec, const float* __restrict__ pos,
    const unsigned short* __restrict__ ADb, const unsigned short* __restrict__ ASb,
    const unsigned short* __restrict__ xvb,
    const float* __restrict__ pW1, const float* __restrict__ pb1,
    const float* __restrict__ pW2, const float* __restrict__ pb2,
    const float* __restrict__ aW1, const float* __restrict__ ab1,
    const float* __restrict__ aW2, const float* __restrict__ ab2,
    float* __restrict__ esum, unsigned* __restrict__ outb,
    int N, int E)
{
    const int tid = threadIdx.x;
    const int lane = tid & 63;
    const int wid  = tid >> 6;
    const int lm = lane & 15;
    const int lg = lane >> 4;

    __shared__ __align__(16) unsigned short swt[3][64 * WPAD];
    __shared__ __align__(16) unsigned short tb[4][16 * WPAD];

    {
        const float* Wsrc[3] = {pW2, aW1, aW2};
        #pragma unroll
        for (int w = 0; w < 3; ++w)
            for (int idx = tid; idx < 4096; idx += 256) {
                int p = idx >> 6, o = idx & 63;
                int c = (p >> 2) + 16*(p & 3);
                swt[w][o*WPAD + p] = f2b(Wsrc[w][(size_t)c*64 + o]);
            }
    }
    __syncthreads();

    // hoisted loop-invariant pW1/pb1 weights, per-lane (bf16-quantized to match prior math)
    float w0v[16], w1v[16], w2v[16], wbv[16];
    #pragma unroll
    for (int j = 0; j < 16; ++j) {
        int p = lg*8 + (j & 7) + 32*(j >> 3);
        int k = (p >> 2) + 16*(p & 3);
        w0v[j] = b2f(f2b(pW1[k]));
        w1v[j] = b2f(f2b(pW1[64 + k]));
        w2v[j] = b2f(f2b(pW1[128 + k]));
        wbv[j] = b2f(f2b(pb1[k]));
    }

    float pb2v[4], ab1v[4], ab2v[4];
    #pragma unroll
    for (int tt = 0; tt < 4; ++tt) {
        pb2v[tt] = pb2[lm + 16*tt];
        ab1v[tt] = ab1[lm + 16*tt];
        ab2v[tt] = ab2[lm + 16*tt];
    }

    unsigned short* tbw = tb[wid];
    const int total = E + N;
    const int ntiles = (total + 15) >> 4;
    const int nwaves = gridDim.x * 4;
    const int tpw = (ntiles + nwaves - 1) / nwaves;
    const int gw = blockIdx.x * 4 + wid;
    const int t0 = min(gw * tpw, ntiles);
    const int t1 = min(t0 + tpw, ntiles);
    if (t0 >= t1) return;
    const int nstep = t1 - t0;
    const int qlen  = 4 * nstep;
    const int rbase = t0 << 4;
    const int pq = rbase + (lm >> 2)*qlen + (lm & 3);
    const int gq = rbase + lg*qlen;

    int   curD = -1;
    bool  firstF = true;
    float sA[4]  = {0.f, 0.f, 0.f, 0.f};
    float mxA[4] = {-INFINITY, -INFINITY, -INFINITY, -INFINITY};

    int2 rp_n, rg_n0, rg_n1, rg_n2, rg_n3;
    rp_n  = rec[min(pq, total-1)];
    rg_n0 = rec[min(gq+0, total-1)];
    rg_n1 = rec[min(gq+1, total-1)];
    rg_n2 = rec[min(gq+2, total-1)];
    rg_n3 = rec[min(gq+3, total-1)];

    for (int step = 0; step < nstep; ++step) {
        const int2 rp = rp_n;
        int sg[4], dg[4];
        sg[0] = rg_n0.x; dg[0] = rg_n0.y;
        sg[1] = rg_n1.x; dg[1] = rg_n1.y;
        sg[2] = rg_n2.x; dg[2] = rg_n2.y;
        sg[3] = rg_n3.x; dg[3] = rg_n3.y;
        int actm = 0;
        #pragma unroll
        for (int r = 0; r < 4; ++r)
            if (gq + step*4 + r < total) actm |= (1 << r);

        float q0 = pos[(size_t)rp.y*3+0] - pos[(size_t)rp.x*3+0];
        float q1 = pos[(size_t)rp.y*3+1] - pos[(size_t)rp.x*3+1];
        float q2 = pos[(size_t)rp.y*3+2] - pos[(size_t)rp.x*3+2];

        float gd[4][4], gxv[4][4];
        #pragma unroll
        for (int r = 0; r < 4; ++r) {
            const ushort4 a4 = *(const ushort4*)&ADb[(size_t)dg[r]*CC + lm*4];
            const ushort4 s4 = *(const ushort4*)&ASb[(size_t)sg[r]*CC + lm*4];
            const ushort4 x4 = *(const ushort4*)&xvb[(size_t)sg[r]*CC + lm*4];
            gd[r][0] = b2f(a4.x) - b2f(s4.x);
            gd[r][1] = b2f(a4.y) - b2f(s4.y);
            gd[r][2] = b2f(a4.z) - b2f(s4.z);
            gd[r][3] = b2f(a4.w) - b2f(s4.w);
            gxv[r][0] = b2f(x4.x); gxv[r][1] = b2f(x4.y);
            gxv[r][2] = b2f(x4.z); gxv[r][3] = b2f(x4.w);
        }

        if (step + 1 < nstep) {
            const int pn = pq + (step+1)*4;
            const int gn = gq + (step+1)*4;
            rp_n  = rec[min(pn,   total-1)];
            rg_n0 = rec[min(gn+0, total-1)];
            rg_n1 = rec[min(gn+1, total-1)];
            rg_n2 = rec[min(gn+2, total-1)];
            rg_n3 = rec[min(gn+3, total-1)];
        }

        // ---- p1 = relu(pdiff@pW1 + pb1) in A-frag layout (registers only) ----
        s16x8 Alo, Ahi;
        #pragma unroll
        for (int j = 0; j < 16; ++j) {
            float v = fmaxf(fmaf(q0, w0v[j], fmaf(q1, w1v[j], fmaf(q2, w2v[j], wbv[j]))), 0.f);
            short b = (short)f2b(v);
            if (j < 8) Alo[j] = b; else Ahi[j-8] = b;
        }

        // ---- layer 1: delta = relu(p1 @ pW2 + pb2) ----
        f32x4 dlt[4];
        #pragma unroll
        for (int tt = 0; tt < 4; ++tt) {
            s16x8 b0 = *(const s16x8*)&swt[0][(lm + 16*tt)*WPAD + lg*8];
            s16x8 b1 = *(const s16x8*)&swt[0][(lm + 16*tt)*WPAD + 32 + lg*8];
            f32x4 z = {0.f, 0.f, 0.f, 0.f};
            z = __builtin_amdgcn_mfma_f32_16x16x32_bf16(Alo, b0, z, 0, 0, 0);
            z = __builtin_amdgcn_mfma_f32_16x16x32_bf16(Ahi, b1, z, 0, 0, 0);
            #pragma unroll
            for (int r = 0; r < 4; ++r) dlt[tt][r] = fmaxf(z[r] + pb2v[tt], 0.f);
        }

        // ---- transpose 1: packed b64 writes (position 4*lm+tt == channel lm+16tt) ----
        #pragma unroll
        for (int r = 0; r < 4; ++r) {
            ushort4 v = make_ushort4(f2b(dlt[0][r]), f2b(dlt[1][r]),
                                     f2b(dlt[2][r]), f2b(dlt[3][r]));
            *(ushort4*)&tbw[(lg*4+r)*WPAD + 4*lm] = v;
        }
        __builtin_amdgcn_wave_barrier();
        s16x8 Dlo = *(const s16x8*)&tbw[lm*WPAD + lg*8];
        s16x8 Dhi = *(const s16x8*)&tbw[lm*WPAD + 32 + lg*8];
        __builtin_amdgcn_wave_barrier();

        // ---- layer 2: h1 = relu(gd + delta@aW1 + ab1) -> packed transpose 2 ----
        float h1v[4][4];
        #pragma unroll
        for (int tt = 0; tt < 4; ++tt) {
            s16x8 b0 = *(const s16x8*)&swt[1][(lm + 16*tt)*WPAD + lg*8];
            s16x8 b1 = *(const s16x8*)&swt[1][(lm + 16*tt)*WPAD + 32 + lg*8];
            f32x4 z = {0.f, 0.f, 0.f, 0.f};
            z = __builtin_amdgcn_mfma_f32_16x16x32_bf16(Dlo, b0, z, 0, 0, 0);
            z = __builtin_amdgcn_mfma_f32_16x16x32_bf16(Dhi, b1, z, 0, 0, 0);
            #pragma unroll
            for (int r = 0; r < 4; ++r)
                h1v[tt][r] = fmaxf(z[r] + gd[r][tt] + ab1v[tt], 0.f);
        }
        #pragma unroll
        for (int r = 0; r < 4; ++r) {
            ushort4 v = make_ushort4(f2b(h1v[0][r]), f2b(h1v[1][r]),
                                     f2b(h1v[2][r]), f2b(h1v[3][r]));
            *(ushort4*)&tbw[(lg*4+r)*WPAD + 4*lm] = v;
        }
        __builtin_amdgcn_wave_barrier();
        s16x8 Hlo = *(const s16x8*)&tbw[lm*WPAD + lg*8];
        s16x8 Hhi = *(const s16x8*)&tbw[lm*WPAD + 32 + lg*8];
        __builtin_amdgcn_wave_barrier();

        // ---- layer 3 + run-carried aggregation ----
        f32x4 zz[4];
        #pragma unroll
        for (int tt = 0; tt < 4; ++tt) {
            s16x8 b0 = *(const s16x8*)&swt[2][(lm + 16*tt)*WPAD + lg*8];
            s16x8 b1 = *(const s16x8*)&swt[2][(lm + 16*tt)*WPAD + 32 + lg*8];
            f32x4 z = {0.f, 0.f, 0.f, 0.f};
            z = __builtin_amdgcn_mfma_f32_16x16x32_bf16(Hlo, b0, z, 0, 0, 0);
            zz[tt] = __builtin_amdgcn_mfma_f32_16x16x32_bf16(Hhi, b1, z, 0, 0, 0);
        }

        #pragma unroll
        for (int r = 0; r < 4; ++r) {
            if (!(actm & (1 << r))) continue;
            if (dg[r] != curD) {
                if (curD >= 0) {
                    if (firstF) {
                        #pragma unroll
                        for (int tt = 0; tt < 4; ++tt) {
                            size_t off = (size_t)curD*CC + lm + 16*tt;
                            atomicAdd(&esum[off], sA[tt]);
                            atomicMax(&outb[off], fmono(mxA[tt]));
                        }
                    } else {
                        #pragma unroll
                        for (int tt = 0; tt < 4; ++tt) {
                            size_t off = (size_t)curD*CC + lm + 16*tt;
                            esum[off] = sA[tt];
                            outb[off] = fmono(mxA[tt]);
                        }
                    }
                    firstF = false;
                }
                curD = dg[r];
                #pragma unroll
                for (int tt = 0; tt < 4; ++tt) { sA[tt] = 0.f; mxA[tt] = -INFINITY; }
            }
            #pragma unroll
            for (int tt = 0; tt < 4; ++tt) {
                float a  = fmaxf(zz[tt][r] + ab2v[tt], 0.f);
                float ee = __expf(a);
                float m  = ee * (gxv[r][tt] + dlt[tt][r]);
                sA[tt] += ee;
                mxA[tt] = fmaxf(mxA[tt], m);
            }
        }
    }

    if (curD >= 0) {
        #pragma unroll
        for (int tt = 0; tt < 4; ++tt) {
            size_t off = (size_t)curD*CC + lm + 16*tt;
            atomicAdd(&esum[off], sA[tt]);
            atomicMax(&outb[off], fmono(mxA[tt]));
        }
    }
}

// ---- output kernel (MFMA), 256 nodes/block -----------------------------------------------
__global__ __launch_bounds__(256, 2) void out_mfma_kernel(
    const unsigned* outb_in,            // aliases out -- no restrict
    const float* __restrict__ esum,
    const float* __restrict__ W_out, const float* __restrict__ b_out,
    float* out, int N)
{
    const int tid = threadIdx.x;
    const int lane = tid & 63;
    const int wid  = tid >> 6;
    const int lm = lane & 15;
    const int lg = lane >> 4;

    __shared__ __align__(16) unsigned short swt[64 * WPAD];
    for (int idx = tid; idx < 4096; idx += 256) {
        int o = idx >> 6, k = idx & 63;
        swt[o*WPAD + k] = f2b(W_out[(size_t)o*64 + k]);
    }
    __syncthreads();

    float bo[4];
    #pragma unroll
    for (int tt = 0; tt < 4; ++tt) bo[tt] = b_out[lm + 16*tt];

    #pragma unroll 1
    for (int g = 0; g < 4; ++g) {
        const int wbase = blockIdx.x * 256 + g * 64 + wid * 16;
        if (wbase >= N) break;

        const int row = min(wbase + lm, N-1);
        const unsigned* up = &outb_in[(size_t)row*CC];
        const float*    ep = &esum[(size_t)row*CC];
        s16x8 Alo, Ahi;
        #pragma unroll
        for (int half = 0; half < 2; ++half) {
            int kb = half*32 + lg*8;
            uint4  u0 = *(const uint4*)&up[kb];
            uint4  u1 = *(const uint4*)&up[kb+4];
            float4 e0 = *(const float4*)&ep[kb];
            float4 e1 = *(const float4*)&ep[kb+4];
            unsigned uu[8] = {u0.x,u0.y,u0.z,u0.w,u1.x,u1.y,u1.z,u1.w};
            float    ee[8] = {e0.x,e0.y,e0.z,e0.w,e1.x,e1.y,e1.z,e1.w};
            #pragma unroll
            for (int j = 0; j < 8; ++j) {
                unsigned u = uu[j];
                u = (u >> 31) ? (u ^ 0x80000000u) : ~u;    // inverse of fmono
                float v = __fdividef(__uint_as_float(u), ee[j]);
                if (half == 0) Alo[j] = (short)f2b(v); else Ahi[j] = (short)f2b(v);
            }
        }

        f32x4 zz[4];
        #pragma unroll
        for (int tt = 0; tt < 4; ++tt) {
            s16x8 b0 = *(const s16x8*)&swt[(lm + 16*tt)*WPAD + lg*8];
            s16x8 b1 = *(const s16x8*)&swt[(lm + 16*tt)*WPAD + 32 + lg*8];
            f32x4 z = {0.f, 0.f, 0.f, 0.f};
            z = __builtin_amdgcn_mfma_f32_16x16x32_bf16(Alo, b0, z, 0, 0, 0);
            zz[tt] = __builtin_amdgcn_mfma_f32_16x16x32_bf16(Ahi, b1, z, 0, 0, 0);
        }

        #pragma unroll
        for (int r = 0; r < 4; ++r) {
            int n = wbase + lg*4 + r;
            if (n < N) {
                #pragma unroll
                for (int tt = 0; tt < 4; ++tt)
                    out[(size_t)n*CC + lm + 16*tt] = fmaxf(zz[tt][r] + bo[tt], 0.f);
            }
        }
    }
}

extern "C" void kernel_launch(void* const* d_in, const int* in_sizes, int n_in,
                              void* d_out, int out_size, void* d_ws, size_t ws_size,
                              hipStream_t stream)
{
    const float* x     = (const float*)d_in[0];
    const float* pos   = (const float*)d_in[1];
    const int*   ei    = (const int*)d_in[2];
    const float* W_in  = (const float*)d_in[3];
    const float* b_in  = (const float*)d_in[4];
    const float* W_out = (const float*)d_in[5];
    const float* b_out = (const float*)d_in[6];
    const float* W_lin = (const float*)d_in[7];
    const float* W_src = (const float*)d_in[8];
    const float* W_dst = (const float*)d_in[9];
    const float* pW1   = (const float*)d_in[10];
    const float* pb1   = (const float*)d_in[11];
    const float* pW2   = (const float*)d_in[12];
    const float* pb2   = (const float*)d_in[13];
    const float* aW1   = (const float*)d_in[14];
    const float* ab1   = (const float*)d_in[15];
    const float* aW2   = (const float*)d_in[16];
    const float* ab2   = (const float*)d_in[17];

    const int N = in_sizes[0] / CC;
    const int E = in_sizes[2] / 2;
    const size_t nc = (size_t)N * CC;

    char* wsb = (char*)d_ws;
    unsigned short* ASb = (unsigned short*)wsb;        // nc * 2B
    unsigned short* ADb = ASb + nc;                    // nc * 2B
    unsigned short* xvb = ADb + nc;                    // nc * 2B
    float* esum = (float*)(((size_t)(xvb + nc) + 15) & ~(size_t)15);   // nc * 4B
    unsigned* cnt       = (unsigned*)(esum + nc);
    unsigned* chunk_off = cnt + N;
    unsigned* cursor    = chunk_off + N;
    unsigned* partials  = cursor + N;                  // 1024 entries
    size_t rec_off = ((size_t)((char*)(partials + 1024) - wsb) + 15) & ~(size_t)15;
    int2* rec = (int2*)(wsb + rec_off);
    unsigned* outb = (unsigned*)d_out;

    // esum and cnt are contiguous -> one memset covers both
    hipMemsetAsync(esum, 0, (nc + (size_t)N)*sizeof(float), stream);
    hipMemsetAsync(outb, 0, nc*sizeof(float), stream);

    const int nblk = (N + 255) / 256;
    node_mfma_kernel<<<nblk, 256, 0, stream>>>(x, W_in, b_in, W_src, W_dst, W_lin, aW1,
                                               ASb, ADb, xvb, ei, cnt, N, E);
    const int nchunks = (N + 1023) / 1024;
    scan1_kernel<<<nchunks, SCAN_T, 0, stream>>>(cnt, chunk_off, partials, N);
    scan2_kernel<<<1, 1024, 0, stream>>>(partials, nchunks);
    scan3_kernel<<<(N + 255)/256, 256, 0, stream>>>(chunk_off, partials, cursor, N);
    scatter_kernel<<<2048, 256, 0, stream>>>(ei, cursor, rec, N, E);
    edge_mfma_kernel<<<2048, 256, 0, stream>>>(rec, pos, ADb, ASb, xvb,
                                               pW1, pb1, pW2, pb2, aW1, ab1, aW2, ab2,
                                               esum, outb, N, E);
    out_mfma_kernel<<<nblk, 256, 0, stream>>>(outb, esum, W_out, b_out, (float*)d_out, N);
}